// Round 1
// baseline (1533.031 us; speedup 1.0000x reference)
//
#include <hip/hip_runtime.h>
#include <hip/hip_bf16.h>
#include <math.h>

#define NNODES 25000
#define NEDGES 400000
#define FIN0 64
#define DHID 128
#define NHEAD 4
#define CDIM 128
#define HC (NHEAD * CDIM)   // 512
#define SCALE 0.088388347648318447f  // 1/sqrt(128)

// ---------------- utility kernels ----------------

__global__ void zero_int_kernel(int* __restrict__ p, int n) {
    int i = blockIdx.x * blockDim.x + threadIdx.x;
    if (i < n) p[i] = 0;
}

__global__ void zero_float_kernel(float* __restrict__ p, int n) {
    int i = blockIdx.x * blockDim.x + threadIdx.x;
    if (i < n) p[i] = 0.f;
}

// ---------------- CSR build ----------------

__global__ void count_kernel(const int* __restrict__ dst, int* __restrict__ deg, int e) {
    int i = blockIdx.x * blockDim.x + threadIdx.x;
    if (i < e) atomicAdd(&deg[dst[i]], 1);
}

// single block, 256 threads: exclusive scan of deg[0..n) -> offs, zero cnt
__global__ void scan_kernel(const int* __restrict__ deg, int* __restrict__ offs,
                            int* __restrict__ cnt, int n, int total) {
    __shared__ int sums[256];
    int t = threadIdx.x;
    int chunk = (n + 255) / 256;
    int b = t * chunk;
    int e = min(b + chunk, n);
    int s = 0;
    for (int i = b; i < e; ++i) s += deg[i];
    sums[t] = s;
    __syncthreads();
    for (int o = 1; o < 256; o <<= 1) {
        int v = (t >= o) ? sums[t - o] : 0;
        __syncthreads();
        sums[t] += v;
        __syncthreads();
    }
    int run = sums[t] - s;  // exclusive prefix of this chunk
    for (int i = b; i < e; ++i) {
        offs[i] = run;
        run += deg[i];
        cnt[i] = 0;
    }
    if (t == 0) offs[n] = total;
}

__global__ void scatter_kernel(const int* __restrict__ src, const int* __restrict__ dst,
                               const int* __restrict__ offs, int* __restrict__ cnt,
                               int* __restrict__ csr, int e) {
    int i = blockIdx.x * blockDim.x + threadIdx.x;
    if (i < e) {
        int d = dst[i];
        int pos = offs[d] + atomicAdd(&cnt[d], 1);
        csr[pos] = src[i];
    }
}

// ---------------- fused QKVS GEMM ----------------
// Out cols: [0,512)=Q, [512,1024)=K, [1024,1536)=V, [1536,1664)=S
// grid: (ceil(n/64), 26), block 256
#define BM 64
#define BN 64
#define BK 16

__global__ __launch_bounds__(256) void gemm_qkvs_kernel(
    const float* __restrict__ X, int n, int fin,
    const float* __restrict__ Wq, const float* __restrict__ bq,
    const float* __restrict__ Wk, const float* __restrict__ bk,
    const float* __restrict__ Wv, const float* __restrict__ bv,
    const float* __restrict__ Ws, const float* __restrict__ bs,
    float* __restrict__ Q, float* __restrict__ K,
    float* __restrict__ V, float* __restrict__ S)
{
    int bm = blockIdx.x;
    int col0 = blockIdx.y * BN;

    const float* W; const float* bias; float* Out; int ldw, oc0, ldo;
    if (col0 < 512)       { W = Wq; bias = bq; Out = Q; ldw = 512; oc0 = col0;        ldo = 512; }
    else if (col0 < 1024) { W = Wk; bias = bk; Out = K; ldw = 512; oc0 = col0 - 512;  ldo = 512; }
    else if (col0 < 1536) { W = Wv; bias = bv; Out = V; ldw = 512; oc0 = col0 - 1024; ldo = 512; }
    else                  { W = Ws; bias = bs; Out = S; ldw = 128; oc0 = col0 - 1536; ldo = 128; }

    __shared__ float Xs[BK][BM + 4];
    __shared__ float Wt[BK][BN];

    int t = threadIdx.x;
    int tx = t & 15, ty = t >> 4;
    int row0 = bm * BM;
    float acc[4][4] = {};

    for (int k0 = 0; k0 < fin; k0 += BK) {
        for (int i = t; i < BM * BK; i += 256) {
            int r = i >> 4, c = i & 15;
            int gr = row0 + r;
            Xs[c][r] = (gr < n) ? X[gr * fin + k0 + c] : 0.f;
        }
        for (int i = t; i < BK * BN; i += 256) {
            int r = i >> 6, c = i & 63;
            Wt[r][c] = W[(k0 + r) * ldw + oc0 + c];
        }
        __syncthreads();
#pragma unroll
        for (int k = 0; k < BK; ++k) {
            float xr[4], wr[4];
#pragma unroll
            for (int i = 0; i < 4; ++i) xr[i] = Xs[k][ty * 4 + i];
#pragma unroll
            for (int j = 0; j < 4; ++j) wr[j] = Wt[k][tx * 4 + j];
#pragma unroll
            for (int i = 0; i < 4; ++i)
#pragma unroll
                for (int j = 0; j < 4; ++j)
                    acc[i][j] += xr[i] * wr[j];
        }
        __syncthreads();
    }

#pragma unroll
    for (int i = 0; i < 4; ++i) {
        int gr = row0 + ty * 4 + i;
        if (gr < n) {
#pragma unroll
            for (int j = 0; j < 4; ++j) {
                int gc = oc0 + tx * 4 + j;
                Out[gr * ldo + gc] = acc[i][j] + bias[gc];
            }
        }
    }
}

// ---------------- fused attention (per dst,head wave, online softmax) ----------------
// grid: N*H/4 blocks of 256 (4 waves/block)
__global__ __launch_bounds__(256) void attn_kernel(
    const float* __restrict__ Q, const float* __restrict__ K,
    const float* __restrict__ V, const int* __restrict__ offs,
    const int* __restrict__ csr, float* __restrict__ tmp, int n)
{
    int wid = (blockIdx.x * blockDim.x + threadIdx.x) >> 6;
    if (wid >= n * NHEAD) return;
    int node = wid >> 2;
    int h = wid & 3;
    int lane = threadIdx.x & 63;
    int base = node * HC + h * CDIM + lane * 2;

    float2 q = *(const float2*)&Q[base];
    int beg = offs[node], end = offs[node + 1];

    float m = -INFINITY, d = 0.f;
    float ax = 0.f, ay = 0.f;
    for (int e = beg; e < end; ++e) {
        int s = csr[e];
        int sb = s * HC + h * CDIM + lane * 2;
        float2 kk = *(const float2*)&K[sb];
        float p = q.x * kk.x + q.y * kk.y;
#pragma unroll
        for (int o = 32; o > 0; o >>= 1) p += __shfl_xor(p, o);
        float alpha = p * SCALE;
        float nm = fmaxf(m, alpha);
        float sc = __expf(m - nm);     // first iter: exp(-inf)=0
        float w = __expf(alpha - nm);
        d = d * sc + w;
        float2 vv = *(const float2*)&V[sb];
        ax = ax * sc + w * vv.x;
        ay = ay * sc + w * vv.y;
        m = nm;
    }
    float inv = (d > 0.f) ? 1.f / d : 0.f;
    float2 out;
    out.x = ax * inv;
    out.y = ay * inv;
    *(float2*)&tmp[base] = out;
}

// ---------------- head mean + skip + relu ----------------
__global__ void combine_kernel(const float* __restrict__ tmp, const float* __restrict__ S,
                               float* __restrict__ Xo, int n) {
    int i = blockIdx.x * blockDim.x + threadIdx.x;
    if (i >= n * DHID) return;
    int nn = i >> 7, c = i & 127;
    const float* tr = tmp + nn * HC;
    float v = (tr[c] + tr[CDIM + c] + tr[2 * CDIM + c] + tr[3 * CDIM + c]) * 0.25f + S[i];
    Xo[i] = fmaxf(v, 0.f);
}

// ---------------- column sum + final sigmoid ----------------
__global__ void colsum_kernel(const float* __restrict__ X, float* __restrict__ g, int n) {
    int c = threadIdx.x;  // 128 threads
    int rpb = (n + gridDim.x - 1) / gridDim.x;
    int r0 = blockIdx.x * rpb;
    int r1 = min(r0 + rpb, n);
    float acc = 0.f;
    for (int r = r0; r < r1; ++r) acc += X[r * DHID + c];
    atomicAdd(&g[c], acc);
}

__global__ void final_kernel(const float* __restrict__ g, const float* __restrict__ Wfc,
                             const float* __restrict__ bfc, float* __restrict__ out, float invn) {
    __shared__ float red[128];
    int t = threadIdx.x;
    red[t] = g[t] * invn * Wfc[t];
    __syncthreads();
    for (int o = 64; o > 0; o >>= 1) {
        if (t < o) red[t] += red[t + o];
        __syncthreads();
    }
    if (t == 0) {
        float z = red[0] + bfc[0];
        out[0] = 1.f / (1.f + expf(-z));
    }
}

// ---------------- host ----------------

extern "C" void kernel_launch(void* const* d_in, const int* in_sizes, int n_in,
                              void* d_out, int out_size, void* d_ws, size_t ws_size,
                              hipStream_t stream) {
    const int N = NNODES, E = NEDGES;
    const float* x = (const float*)d_in[0];
    const int* ei = (const int*)d_in[1];
    const int* src = ei;
    const int* dst = ei + E;
    const float* Wfc = (const float*)d_in[26];
    const float* bfc = (const float*)d_in[27];

    // workspace layout
    size_t off = 0;
    auto alloc = [&](size_t bytes) -> char* {
        char* p = (char*)d_ws + off;
        off += (bytes + 255) & ~(size_t)255;
        return p;
    };
    int* deg   = (int*)alloc((size_t)N * 4);
    int* cnt   = (int*)alloc((size_t)N * 4);
    int* offs  = (int*)alloc((size_t)(N + 1) * 4);
    int* csr   = (int*)alloc((size_t)E * 4);
    float* Q   = (float*)alloc((size_t)N * HC * 4);
    float* K   = (float*)alloc((size_t)N * HC * 4);
    float* V   = (float*)alloc((size_t)N * HC * 4);
    float* S   = (float*)alloc((size_t)N * DHID * 4);
    float* tmp = (float*)alloc((size_t)N * HC * 4);
    float* x1  = (float*)alloc((size_t)N * DHID * 4);
    float* x2  = (float*)alloc((size_t)N * DHID * 4);
    float* g   = (float*)alloc(128 * 4);

    // CSR build (same graph for all layers)
    zero_int_kernel<<<(N + 255) / 256, 256, 0, stream>>>(deg, N);
    zero_float_kernel<<<1, 128, 0, stream>>>(g, 128);
    count_kernel<<<(E + 255) / 256, 256, 0, stream>>>(dst, deg, E);
    scan_kernel<<<1, 256, 0, stream>>>(deg, offs, cnt, N, E);
    scatter_kernel<<<(E + 255) / 256, 256, 0, stream>>>(src, dst, offs, cnt, csr, E);

    dim3 ggrid((N + BM - 1) / BM, 1664 / BN);
    int attn_blocks = (N * NHEAD + 3) / 4;
    int comb_blocks = (N * DHID + 255) / 256;

    const float* xin = x;
    float* xouts[3] = { x1, x2, x1 };
    for (int l = 0; l < 3; ++l) {
        int fin = (l == 0) ? FIN0 : DHID;
        const float* Wq = (const float*)d_in[2 + l * 8 + 0];
        const float* bq = (const float*)d_in[2 + l * 8 + 1];
        const float* Wk = (const float*)d_in[2 + l * 8 + 2];
        const float* bk = (const float*)d_in[2 + l * 8 + 3];
        const float* Wv = (const float*)d_in[2 + l * 8 + 4];
        const float* bv = (const float*)d_in[2 + l * 8 + 5];
        const float* Wss= (const float*)d_in[2 + l * 8 + 6];
        const float* bs = (const float*)d_in[2 + l * 8 + 7];

        gemm_qkvs_kernel<<<ggrid, 256, 0, stream>>>(xin, N, fin,
            Wq, bq, Wk, bk, Wv, bv, Wss, bs, Q, K, V, S);
        attn_kernel<<<attn_blocks, 256, 0, stream>>>(Q, K, V, offs, csr, tmp, N);
        combine_kernel<<<comb_blocks, 256, 0, stream>>>(tmp, S, xouts[l], N);
        xin = xouts[l];
    }

    colsum_kernel<<<256, 128, 0, stream>>>(x1, g, N);
    final_kernel<<<1, 128, 0, stream>>>(g, Wfc, bfc, (float*)d_out, 1.0f / N);
}

// Round 2
// 1134.641 us; speedup vs baseline: 1.3511x; 1.3511x over previous
//
#include <hip/hip_runtime.h>
#include <hip/hip_bf16.h>
#include <math.h>

#define NNODES 25000
#define NEDGES 400000
#define FIN0 64
#define DHID 128
#define NHEAD 4
#define CDIM 128
#define HC (NHEAD * CDIM)   // 512
#define SCALE 0.088388347648318447f  // 1/sqrt(128)

// ---------------- utility kernels ----------------

__global__ void zero_int_kernel(int* __restrict__ p, int n) {
    int i = blockIdx.x * blockDim.x + threadIdx.x;
    if (i < n) p[i] = 0;
}

__global__ void zero_float_kernel(float* __restrict__ p, int n) {
    int i = blockIdx.x * blockDim.x + threadIdx.x;
    if (i < n) p[i] = 0.f;
}

// ---------------- CSR build ----------------

__global__ void count_kernel(const int* __restrict__ dst, int* __restrict__ deg, int e) {
    int i = blockIdx.x * blockDim.x + threadIdx.x;
    if (i < e) atomicAdd(&deg[dst[i]], 1);
}

// single block, 256 threads: exclusive scan of deg[0..n) -> offs, zero cnt
__global__ void scan_kernel(const int* __restrict__ deg, int* __restrict__ offs,
                            int* __restrict__ cnt, int n, int total) {
    __shared__ int sums[256];
    int t = threadIdx.x;
    int chunk = (n + 255) / 256;
    int b = t * chunk;
    int e = min(b + chunk, n);
    int s = 0;
    for (int i = b; i < e; ++i) s += deg[i];
    sums[t] = s;
    __syncthreads();
    for (int o = 1; o < 256; o <<= 1) {
        int v = (t >= o) ? sums[t - o] : 0;
        __syncthreads();
        sums[t] += v;
        __syncthreads();
    }
    int run = sums[t] - s;  // exclusive prefix of this chunk
    for (int i = b; i < e; ++i) {
        offs[i] = run;
        run += deg[i];
        cnt[i] = 0;
    }
    if (t == 0) offs[n] = total;
}

__global__ void scatter_kernel(const int* __restrict__ src, const int* __restrict__ dst,
                               const int* __restrict__ offs, int* __restrict__ cnt,
                               int* __restrict__ csr, int e) {
    int i = blockIdx.x * blockDim.x + threadIdx.x;
    if (i < e) {
        int d = dst[i];
        int pos = offs[d] + atomicAdd(&cnt[d], 1);
        csr[pos] = src[i];
    }
}

// ---------------- fused QKVS GEMM ----------------
// Out cols: [0,512)=Q fp32, [512,1024)=K bf16, [1024,1536)=V bf16, [1536,1664)=S fp32
// grid: (ceil(n/64), 26), block 256
#define BM 64
#define BN 64
#define BK 16

__global__ __launch_bounds__(256) void gemm_qkvs_kernel(
    const float* __restrict__ X, int n, int fin,
    const float* __restrict__ Wq, const float* __restrict__ bq,
    const float* __restrict__ Wk, const float* __restrict__ bk,
    const float* __restrict__ Wv, const float* __restrict__ bv,
    const float* __restrict__ Ws, const float* __restrict__ bs,
    float* __restrict__ Q, __hip_bfloat16* __restrict__ Kb,
    __hip_bfloat16* __restrict__ Vb, float* __restrict__ S)
{
    int bm = blockIdx.x;
    int col0 = blockIdx.y * BN;

    const float* W; const float* bias; int ldw, oc0;
    int kind;  // 0=Q,1=K,2=V,3=S
    if (col0 < 512)       { W = Wq; bias = bq; ldw = 512; oc0 = col0;        kind = 0; }
    else if (col0 < 1024) { W = Wk; bias = bk; ldw = 512; oc0 = col0 - 512;  kind = 1; }
    else if (col0 < 1536) { W = Wv; bias = bv; ldw = 512; oc0 = col0 - 1024; kind = 2; }
    else                  { W = Ws; bias = bs; ldw = 128; oc0 = col0 - 1536; kind = 3; }

    __shared__ float Xs[BK][BM + 4];
    __shared__ float Wt[BK][BN];

    int t = threadIdx.x;
    int tx = t & 15, ty = t >> 4;
    int row0 = bm * BM;
    float acc[4][4] = {};

    for (int k0 = 0; k0 < fin; k0 += BK) {
        for (int i = t; i < BM * BK; i += 256) {
            int r = i >> 4, c = i & 15;
            int gr = row0 + r;
            Xs[c][r] = (gr < n) ? X[gr * fin + k0 + c] : 0.f;
        }
        for (int i = t; i < BK * BN; i += 256) {
            int r = i >> 6, c = i & 63;
            Wt[r][c] = W[(k0 + r) * ldw + oc0 + c];
        }
        __syncthreads();
#pragma unroll
        for (int k = 0; k < BK; ++k) {
            float xr[4], wr[4];
#pragma unroll
            for (int i = 0; i < 4; ++i) xr[i] = Xs[k][ty * 4 + i];
#pragma unroll
            for (int j = 0; j < 4; ++j) wr[j] = Wt[k][tx * 4 + j];
#pragma unroll
            for (int i = 0; i < 4; ++i)
#pragma unroll
                for (int j = 0; j < 4; ++j)
                    acc[i][j] += xr[i] * wr[j];
        }
        __syncthreads();
    }

#pragma unroll
    for (int i = 0; i < 4; ++i) {
        int gr = row0 + ty * 4 + i;
        if (gr < n) {
#pragma unroll
            for (int j = 0; j < 4; ++j) {
                int gc = oc0 + tx * 4 + j;
                float val = acc[i][j] + bias[gc];
                if (kind == 0)      Q[gr * 512 + gc] = val;
                else if (kind == 1) Kb[gr * 512 + gc] = __float2bfloat16(val);
                else if (kind == 2) Vb[gr * 512 + gc] = __float2bfloat16(val);
                else                S[gr * 128 + gc] = val;
            }
        }
    }
}

// ---------------- fused attention ----------------
// One wave per dst node, all 4 heads. Lane i owns channels [8i, 8i+8) of the
// 512-wide K/V rows (head = lane>>4). Online softmax per 16-lane head group.

__device__ __forceinline__ void unpack8(uint4 r, float* f) {
    f[0] = __uint_as_float(r.x << 16);
    f[1] = __uint_as_float(r.x & 0xffff0000u);
    f[2] = __uint_as_float(r.y << 16);
    f[3] = __uint_as_float(r.y & 0xffff0000u);
    f[4] = __uint_as_float(r.z << 16);
    f[5] = __uint_as_float(r.z & 0xffff0000u);
    f[6] = __uint_as_float(r.w << 16);
    f[7] = __uint_as_float(r.w & 0xffff0000u);
}

__device__ __forceinline__ float dot8(const float* q, uint4 r) {
    float f[8];
    unpack8(r, f);
    float p = 0.f;
#pragma unroll
    for (int j = 0; j < 8; ++j) p = fmaf(q[j], f[j], p);
    return p;
}

__device__ __forceinline__ void upd(float& m, float& d, float* acc,
                                    float alpha, uint4 vr) {
    float vf[8];
    unpack8(vr, vf);
    float nm = fmaxf(m, alpha);
    float sc = __expf(m - nm);    // first iter: exp(-inf)=0
    float w  = __expf(alpha - nm);
    d = d * sc + w;
#pragma unroll
    for (int j = 0; j < 8; ++j) acc[j] = acc[j] * sc + w * vf[j];
    m = nm;
}

__global__ __launch_bounds__(256) void attn_kernel(
    const float* __restrict__ Q, const __hip_bfloat16* __restrict__ Kb,
    const __hip_bfloat16* __restrict__ Vb, const int* __restrict__ offs,
    const int* __restrict__ csr, float* __restrict__ tmp, int n)
{
    int node = (blockIdx.x * blockDim.x + threadIdx.x) >> 6;
    if (node >= n) return;
    int lane = threadIdx.x & 63;
    int base = node * HC + lane * 8;

    float qf[8];
    {
        const float4* qp = (const float4*)&Q[base];
        float4 a = qp[0], b = qp[1];
        qf[0] = a.x; qf[1] = a.y; qf[2] = a.z; qf[3] = a.w;
        qf[4] = b.x; qf[5] = b.y; qf[6] = b.z; qf[7] = b.w;
    }

    int beg = offs[node], end = offs[node + 1];
    float m = -INFINITY, d = 0.f;
    float acc[8] = {};

    int e = beg;
    for (; e + 1 < end; e += 2) {
        int s0 = csr[e], s1 = csr[e + 1];
        const __hip_bfloat16* k0p = Kb + (size_t)s0 * HC + lane * 8;
        const __hip_bfloat16* k1p = Kb + (size_t)s1 * HC + lane * 8;
        const __hip_bfloat16* v0p = Vb + (size_t)s0 * HC + lane * 8;
        const __hip_bfloat16* v1p = Vb + (size_t)s1 * HC + lane * 8;
        uint4 kr0 = *(const uint4*)k0p;
        uint4 kr1 = *(const uint4*)k1p;
        uint4 vr0 = *(const uint4*)v0p;
        uint4 vr1 = *(const uint4*)v1p;
        float p0 = dot8(qf, kr0);
        float p1 = dot8(qf, kr1);
#pragma unroll
        for (int o = 1; o < 16; o <<= 1) {
            p0 += __shfl_xor(p0, o);
            p1 += __shfl_xor(p1, o);
        }
        upd(m, d, acc, p0 * SCALE, vr0);
        upd(m, d, acc, p1 * SCALE, vr1);
    }
    if (e < end) {
        int s0 = csr[e];
        uint4 kr0 = *(const uint4*)(Kb + (size_t)s0 * HC + lane * 8);
        uint4 vr0 = *(const uint4*)(Vb + (size_t)s0 * HC + lane * 8);
        float p0 = dot8(qf, kr0);
#pragma unroll
        for (int o = 1; o < 16; o <<= 1) p0 += __shfl_xor(p0, o);
        upd(m, d, acc, p0 * SCALE, vr0);
    }

    float inv = (d > 0.f) ? 1.f / d : 0.f;
    float4 o0, o1;
    o0.x = acc[0] * inv; o0.y = acc[1] * inv; o0.z = acc[2] * inv; o0.w = acc[3] * inv;
    o1.x = acc[4] * inv; o1.y = acc[5] * inv; o1.z = acc[6] * inv; o1.w = acc[7] * inv;
    float4* op = (float4*)&tmp[base];
    op[0] = o0;
    op[1] = o1;
}

// ---------------- head mean + skip + relu ----------------
__global__ void combine_kernel(const float* __restrict__ tmp, const float* __restrict__ S,
                               float* __restrict__ Xo, int n) {
    int i = blockIdx.x * blockDim.x + threadIdx.x;
    if (i >= n * DHID) return;
    int nn = i >> 7, c = i & 127;
    const float* tr = tmp + nn * HC;
    float v = (tr[c] + tr[CDIM + c] + tr[2 * CDIM + c] + tr[3 * CDIM + c]) * 0.25f + S[i];
    Xo[i] = fmaxf(v, 0.f);
}

// ---------------- column sum + final sigmoid ----------------
__global__ void colsum_kernel(const float* __restrict__ X, float* __restrict__ g, int n) {
    int c = threadIdx.x;  // 128 threads
    int rpb = (n + gridDim.x - 1) / gridDim.x;
    int r0 = blockIdx.x * rpb;
    int r1 = min(r0 + rpb, n);
    float acc = 0.f;
    for (int r = r0; r < r1; ++r) acc += X[r * DHID + c];
    atomicAdd(&g[c], acc);
}

__global__ void final_kernel(const float* __restrict__ g, const float* __restrict__ Wfc,
                             const float* __restrict__ bfc, float* __restrict__ out, float invn) {
    __shared__ float red[128];
    int t = threadIdx.x;
    red[t] = g[t] * invn * Wfc[t];
    __syncthreads();
    for (int o = 64; o > 0; o >>= 1) {
        if (t < o) red[t] += red[t + o];
        __syncthreads();
    }
    if (t == 0) {
        float z = red[0] + bfc[0];
        out[0] = 1.f / (1.f + expf(-z));
    }
}

// ---------------- host ----------------

extern "C" void kernel_launch(void* const* d_in, const int* in_sizes, int n_in,
                              void* d_out, int out_size, void* d_ws, size_t ws_size,
                              hipStream_t stream) {
    const int N = NNODES, E = NEDGES;
    const float* x = (const float*)d_in[0];
    const int* ei = (const int*)d_in[1];
    const int* src = ei;
    const int* dst = ei + E;
    const float* Wfc = (const float*)d_in[26];
    const float* bfc = (const float*)d_in[27];

    // workspace layout
    size_t off = 0;
    auto alloc = [&](size_t bytes) -> char* {
        char* p = (char*)d_ws + off;
        off += (bytes + 255) & ~(size_t)255;
        return p;
    };
    int* deg   = (int*)alloc((size_t)N * 4);
    int* cnt   = (int*)alloc((size_t)N * 4);
    int* offs  = (int*)alloc((size_t)(N + 1) * 4);
    int* csr   = (int*)alloc((size_t)E * 4);
    float* Q   = (float*)alloc((size_t)N * HC * 4);
    __hip_bfloat16* Kb = (__hip_bfloat16*)alloc((size_t)N * HC * 2);
    __hip_bfloat16* Vb = (__hip_bfloat16*)alloc((size_t)N * HC * 2);
    float* S   = (float*)alloc((size_t)N * DHID * 4);
    float* tmp = (float*)alloc((size_t)N * HC * 4);
    float* x1  = (float*)alloc((size_t)N * DHID * 4);
    float* x2  = (float*)alloc((size_t)N * DHID * 4);
    float* g   = (float*)alloc(128 * 4);

    // CSR build (same graph for all layers)
    zero_int_kernel<<<(N + 255) / 256, 256, 0, stream>>>(deg, N);
    zero_float_kernel<<<1, 128, 0, stream>>>(g, 128);
    count_kernel<<<(E + 255) / 256, 256, 0, stream>>>(dst, deg, E);
    scan_kernel<<<1, 256, 0, stream>>>(deg, offs, cnt, N, E);
    scatter_kernel<<<(E + 255) / 256, 256, 0, stream>>>(src, dst, offs, cnt, csr, E);

    dim3 ggrid((N + BM - 1) / BM, 1664 / BN);
    int attn_blocks = (N + 3) / 4;   // 1 wave per node, 4 waves/block
    int comb_blocks = (N * DHID + 255) / 256;

    const float* xin = x;
    float* xouts[3] = { x1, x2, x1 };
    for (int l = 0; l < 3; ++l) {
        int fin = (l == 0) ? FIN0 : DHID;
        const float* Wq = (const float*)d_in[2 + l * 8 + 0];
        const float* bq = (const float*)d_in[2 + l * 8 + 1];
        const float* Wk = (const float*)d_in[2 + l * 8 + 2];
        const float* bk = (const float*)d_in[2 + l * 8 + 3];
        const float* Wv = (const float*)d_in[2 + l * 8 + 4];
        const float* bv = (const float*)d_in[2 + l * 8 + 5];
        const float* Wss= (const float*)d_in[2 + l * 8 + 6];
        const float* bs = (const float*)d_in[2 + l * 8 + 7];

        gemm_qkvs_kernel<<<ggrid, 256, 0, stream>>>(xin, N, fin,
            Wq, bq, Wk, bk, Wv, bv, Wss, bs, Q, Kb, Vb, S);
        attn_kernel<<<attn_blocks, 256, 0, stream>>>(Q, Kb, Vb, offs, csr, tmp, N);
        combine_kernel<<<comb_blocks, 256, 0, stream>>>(tmp, S, xouts[l], N);
        xin = xouts[l];
    }

    colsum_kernel<<<256, 128, 0, stream>>>(x1, g, N);
    final_kernel<<<1, 128, 0, stream>>>(g, Wfc, bfc, (float*)d_out, 1.0f / N);
}

// Round 4
// 845.354 us; speedup vs baseline: 1.8135x; 1.3422x over previous
//
#include <hip/hip_runtime.h>
#include <hip/hip_bf16.h>
#include <math.h>

#define NNODES 25000
#define NEDGES 400000
#define FIN0 64
#define DHID 128
#define NHEAD 4
#define CDIM 128
#define HC (NHEAD * CDIM)   // 512
#define NOUT 1664           // Q512 | K512 | V512 | S128
#define SCALE 0.088388347648318447f  // 1/sqrt(128)

typedef __attribute__((ext_vector_type(8))) short short8;
typedef __attribute__((ext_vector_type(4))) float floatx4;

__device__ __forceinline__ short f2bf(float v) {
    unsigned u = __float_as_uint(v);
    u = (u + 0x7fffu + ((u >> 16) & 1u)) >> 16;   // RNE
    return (short)u;
}
__device__ __forceinline__ float bf2f(short s) {
    return __uint_as_float(((unsigned)(unsigned short)s) << 16);
}

// ---------------- utility kernels ----------------

__global__ void zero_int_kernel(int* __restrict__ p, int n) {
    int i = blockIdx.x * blockDim.x + threadIdx.x;
    if (i < n) p[i] = 0;
}

__global__ void zero_float_kernel(float* __restrict__ p, int n) {
    int i = blockIdx.x * blockDim.x + threadIdx.x;
    if (i < n) p[i] = 0.f;
}

__global__ void cvt_x_kernel(const float* __restrict__ x, short* __restrict__ xb, int total) {
    int i = blockIdx.x * blockDim.x + threadIdx.x;
    if (i < total) xb[i] = f2bf(x[i]);
}

// Build WcatT[1664][fin] (bf16, transposed) + bcat[1664] (fp32).
// finShift = log2(fin)
__global__ void cvt_w_kernel(const float* __restrict__ Wq, const float* __restrict__ Wk,
                             const float* __restrict__ Wv, const float* __restrict__ Ws,
                             const float* __restrict__ bq, const float* __restrict__ bk,
                             const float* __restrict__ bv, const float* __restrict__ bs,
                             short* __restrict__ WT, float* __restrict__ bc, int finShift) {
    int idx = blockIdx.x * blockDim.x + threadIdx.x;
    int fin = 1 << finShift;
    int total = NOUT << finShift;
    if (idx < total) {
        int c = idx >> finShift;
        int k = idx & (fin - 1);
        float v;
        if (c < 512)       v = Wq[k * 512 + c];
        else if (c < 1024) v = Wk[k * 512 + c - 512];
        else if (c < 1536) v = Wv[k * 512 + c - 1024];
        else               v = Ws[k * 128 + c - 1536];
        WT[idx] = f2bf(v);
    }
    if (idx < NOUT) {
        int c = idx;
        float b;
        if (c < 512)       b = bq[c];
        else if (c < 1024) b = bk[c - 512];
        else if (c < 1536) b = bv[c - 1024];
        else               b = bs[c - 1536];
        bc[c] = b;
    }
}

// ---------------- CSR build ----------------

__global__ void count_kernel(const int* __restrict__ dst, int* __restrict__ deg, int e) {
    int i = blockIdx.x * blockDim.x + threadIdx.x;
    if (i < e) atomicAdd(&deg[dst[i]], 1);
}

__global__ void scan_kernel(const int* __restrict__ deg, int* __restrict__ offs,
                            int* __restrict__ cnt, int n, int total) {
    __shared__ int sums[256];
    int t = threadIdx.x;
    int chunk = (n + 255) / 256;
    int b = t * chunk;
    int e = min(b + chunk, n);
    int s = 0;
    for (int i = b; i < e; ++i) s += deg[i];
    sums[t] = s;
    __syncthreads();
    for (int o = 1; o < 256; o <<= 1) {
        int v = (t >= o) ? sums[t - o] : 0;
        __syncthreads();
        sums[t] += v;
        __syncthreads();
    }
    int run = sums[t] - s;
    for (int i = b; i < e; ++i) {
        offs[i] = run;
        run += deg[i];
        cnt[i] = 0;
    }
    if (t == 0) offs[n] = total;
}

__global__ void scatter_kernel(const int* __restrict__ src, const int* __restrict__ dst,
                               const int* __restrict__ offs, int* __restrict__ cnt,
                               int* __restrict__ csr, int e) {
    int i = blockIdx.x * blockDim.x + threadIdx.x;
    if (i < e) {
        int d = dst[i];
        int pos = offs[d] + atomicAdd(&cnt[d], 1);
        csr[pos] = src[i];
    }
}

// ---------------- fused QKVS GEMM (bf16 MFMA) ----------------
// C = Xb[n x fin] @ Wcat[fin x 1664] + bcat.  Tile 64x64, 4 waves of 32x32.
// Out: cols [0,512) -> Q fp32, [512,1024) -> Kb bf16, [1024,1536) -> Vb bf16,
//      [1536,1664) -> S fp32.
__global__ __launch_bounds__(256) void gemm_qkvs_mfma(
    const short* __restrict__ Xb, int n, int finShift,
    const short* __restrict__ WT, const float* __restrict__ bc,
    float* __restrict__ Q, short* __restrict__ Kb,
    short* __restrict__ Vb, float* __restrict__ S)
{
    __shared__ short Xs[64][136];   // +8 pad breaks bank alias on frag reads
    __shared__ short Wt[64][136];

    int t = threadIdx.x;
    int row0 = blockIdx.x * 64, col0 = blockIdx.y * 64;
    int fin = 1 << finShift;
    int cs = finShift - 3;            // chunks-of-8 per row shift
    int cmask = (1 << cs) - 1;

    for (int i = t; i < (64 << cs); i += 256) {
        int r = i >> cs, c = (i & cmask) * 8;
        int gr = row0 + r;
        uint4 v = make_uint4(0u, 0u, 0u, 0u);
        if (gr < n) v = *(const uint4*)&Xb[(size_t)gr * fin + c];
        *(uint4*)&Xs[r][c] = v;
    }
    for (int i = t; i < (64 << cs); i += 256) {
        int r = i >> cs, c = (i & cmask) * 8;
        *(uint4*)&Wt[r][c] = *(const uint4*)&WT[((size_t)(col0 + r) << finShift) + c];
    }
    __syncthreads();

    int l = t & 63, w = t >> 6;
    int wr = (w >> 1) * 32, wc = (w & 1) * 32;
    int lr = l & 15, lk = (l >> 4) * 8;

    floatx4 acc[2][2] = {};
    for (int k0 = 0; k0 < fin; k0 += 32) {
        short8 a0 = *(const short8*)&Xs[wr + lr][k0 + lk];
        short8 a1 = *(const short8*)&Xs[wr + 16 + lr][k0 + lk];
        short8 b0 = *(const short8*)&Wt[wc + lr][k0 + lk];
        short8 b1 = *(const short8*)&Wt[wc + 16 + lr][k0 + lk];
        acc[0][0] = __builtin_amdgcn_mfma_f32_16x16x32_bf16(a0, b0, acc[0][0], 0, 0, 0);
        acc[0][1] = __builtin_amdgcn_mfma_f32_16x16x32_bf16(a0, b1, acc[0][1], 0, 0, 0);
        acc[1][0] = __builtin_amdgcn_mfma_f32_16x16x32_bf16(a1, b0, acc[1][0], 0, 0, 0);
        acc[1][1] = __builtin_amdgcn_mfma_f32_16x16x32_bf16(a1, b1, acc[1][1], 0, 0, 0);
    }

    int rb = (l >> 4) * 4;
    int cl = l & 15;
#pragma unroll
    for (int mi = 0; mi < 2; ++mi) {
#pragma unroll
        for (int ni = 0; ni < 2; ++ni) {
            int gc = col0 + wc + ni * 16 + cl;
            float bias = bc[gc];
#pragma unroll
            for (int r = 0; r < 4; ++r) {
                int gr = row0 + wr + mi * 16 + rb + r;
                if (gr < n) {
                    float v = acc[mi][ni][r] + bias;
                    if (gc < 512)       Q[(size_t)gr * 512 + gc] = v;
                    else if (gc < 1024) Kb[(size_t)gr * 512 + gc - 512] = f2bf(v);
                    else if (gc < 1536) Vb[(size_t)gr * 512 + gc - 1024] = f2bf(v);
                    else                S[(size_t)gr * 128 + gc - 1536] = v;
                }
            }
        }
    }
}

// ---------------- fused attention ----------------
// One wave per dst node, all 4 heads. Lane i owns channels [8i, 8i+8) of the
// 512-wide K/V rows (head = lane>>4). Online softmax per 16-lane head group.

__device__ __forceinline__ void unpack8(uint4 r, float* f) {
    f[0] = __uint_as_float(r.x << 16);
    f[1] = __uint_as_float(r.x & 0xffff0000u);
    f[2] = __uint_as_float(r.y << 16);
    f[3] = __uint_as_float(r.y & 0xffff0000u);
    f[4] = __uint_as_float(r.z << 16);
    f[5] = __uint_as_float(r.z & 0xffff0000u);
    f[6] = __uint_as_float(r.w << 16);
    f[7] = __uint_as_float(r.w & 0xffff0000u);
}

__device__ __forceinline__ float dot8(const float* q, uint4 r) {
    float f[8];
    unpack8(r, f);
    float p = 0.f;
#pragma unroll
    for (int j = 0; j < 8; ++j) p = fmaf(q[j], f[j], p);
    return p;
}

__device__ __forceinline__ void upd(float& m, float& d, float* acc,
                                    float alpha, uint4 vr) {
    float vf[8];
    unpack8(vr, vf);
    float nm = fmaxf(m, alpha);
    float sc = __expf(m - nm);    // first iter: exp(-inf)=0
    float w  = __expf(alpha - nm);
    d = d * sc + w;
#pragma unroll
    for (int j = 0; j < 8; ++j) acc[j] = acc[j] * sc + w * vf[j];
    m = nm;
}

__global__ __launch_bounds__(256) void attn_kernel(
    const float* __restrict__ Q, const short* __restrict__ Kb,
    const short* __restrict__ Vb, const int* __restrict__ offs,
    const int* __restrict__ csr, float* __restrict__ tmp, int n)
{
    int node = (blockIdx.x * blockDim.x + threadIdx.x) >> 6;
    if (node >= n) return;
    int lane = threadIdx.x & 63;
    int base = node * HC + lane * 8;

    float qf[8];
    {
        const float4* qp = (const float4*)&Q[base];
        float4 a = qp[0], b = qp[1];
        qf[0] = a.x; qf[1] = a.y; qf[2] = a.z; qf[3] = a.w;
        qf[4] = b.x; qf[5] = b.y; qf[6] = b.z; qf[7] = b.w;
    }

    int beg = offs[node], end = offs[node + 1];
    float m = -INFINITY, d = 0.f;
    float acc[8] = {};

    int e = beg;
    for (; e + 1 < end; e += 2) {
        int s0 = csr[e], s1 = csr[e + 1];
        uint4 kr0 = *(const uint4*)(Kb + (size_t)s0 * HC + lane * 8);
        uint4 kr1 = *(const uint4*)(Kb + (size_t)s1 * HC + lane * 8);
        uint4 vr0 = *(const uint4*)(Vb + (size_t)s0 * HC + lane * 8);
        uint4 vr1 = *(const uint4*)(Vb + (size_t)s1 * HC + lane * 8);
        float p0 = dot8(qf, kr0);
        float p1 = dot8(qf, kr1);
#pragma unroll
        for (int o = 1; o < 16; o <<= 1) {
            p0 += __shfl_xor(p0, o);
            p1 += __shfl_xor(p1, o);
        }
        upd(m, d, acc, p0 * SCALE, vr0);
        upd(m, d, acc, p1 * SCALE, vr1);
    }
    if (e < end) {
        int s0 = csr[e];
        uint4 kr0 = *(const uint4*)(Kb + (size_t)s0 * HC + lane * 8);
        uint4 vr0 = *(const uint4*)(Vb + (size_t)s0 * HC + lane * 8);
        float p0 = dot8(qf, kr0);
#pragma unroll
        for (int o = 1; o < 16; o <<= 1) p0 += __shfl_xor(p0, o);
        upd(m, d, acc, p0 * SCALE, vr0);
    }

    float inv = (d > 0.f) ? 1.f / d : 0.f;
    float4 o0, o1;
    o0.x = acc[0] * inv; o0.y = acc[1] * inv; o0.z = acc[2] * inv; o0.w = acc[3] * inv;
    o1.x = acc[4] * inv; o1.y = acc[5] * inv; o1.z = acc[6] * inv; o1.w = acc[7] * inv;
    float4* op = (float4*)&tmp[base];
    op[0] = o0;
    op[1] = o1;
}

// ---------------- head mean + skip + relu -> bf16 activations ----------------
__global__ void combine_kernel(const float* __restrict__ tmp, const float* __restrict__ S,
                               short* __restrict__ Xo, int n) {
    int i = blockIdx.x * blockDim.x + threadIdx.x;
    if (i >= n * DHID) return;
    int nn = i >> 7, c = i & 127;
    const float* tr = tmp + nn * HC;
    float v = (tr[c] + tr[CDIM + c] + tr[2 * CDIM + c] + tr[3 * CDIM + c]) * 0.25f + S[i];
    Xo[i] = f2bf(fmaxf(v, 0.f));
}

// ---------------- column sum + final sigmoid ----------------
__global__ void colsum_kernel(const short* __restrict__ X, float* __restrict__ g, int n) {
    int c = threadIdx.x;  // 128 threads
    int rpb = (n + gridDim.x - 1) / gridDim.x;
    int r0 = blockIdx.x * rpb;
    int r1 = min(r0 + rpb, n);
    float acc = 0.f;
    for (int r = r0; r < r1; ++r) acc += bf2f(X[r * DHID + c]);
    atomicAdd(&g[c], acc);
}

__global__ void final_kernel(const float* __restrict__ g, const float* __restrict__ Wfc,
                             const float* __restrict__ bfc, float* __restrict__ out, float invn) {
    __shared__ float red[128];
    int t = threadIdx.x;
    red[t] = g[t] * invn * Wfc[t];
    __syncthreads();
    for (int o = 64; o > 0; o >>= 1) {
        if (t < o) red[t] += red[t + o];
        __syncthreads();
    }
    if (t == 0) {
        float z = red[0] + bfc[0];
        out[0] = 1.f / (1.f + expf(-z));
    }
}

// ---------------- host ----------------

extern "C" void kernel_launch(void* const* d_in, const int* in_sizes, int n_in,
                              void* d_out, int out_size, void* d_ws, size_t ws_size,
                              hipStream_t stream) {
    const int N = NNODES, E = NEDGES;
    const float* x = (const float*)d_in[0];
    const int* ei = (const int*)d_in[1];
    const int* src = ei;
    const int* dst = ei + E;
    const float* Wfc = (const float*)d_in[26];
    const float* bfc = (const float*)d_in[27];

    // workspace layout
    size_t off = 0;
    auto alloc = [&](size_t bytes) -> char* {
        char* p = (char*)d_ws + off;
        off += (bytes + 255) & ~(size_t)255;
        return p;
    };
    int* deg   = (int*)alloc((size_t)N * 4);
    int* cnt   = (int*)alloc((size_t)N * 4);
    int* offs  = (int*)alloc((size_t)(N + 1) * 4);
    int* csr   = (int*)alloc((size_t)E * 4);
    float* Q   = (float*)alloc((size_t)N * HC * 4);
    short* Kb  = (short*)alloc((size_t)N * HC * 2);
    short* Vb  = (short*)alloc((size_t)N * HC * 2);
    float* S   = (float*)alloc((size_t)N * DHID * 4);
    float* tmp = (float*)alloc((size_t)N * HC * 4);
    short* xb0 = (short*)alloc((size_t)N * FIN0 * 2);
    short* xb1 = (short*)alloc((size_t)N * DHID * 2);
    short* xb2 = (short*)alloc((size_t)N * DHID * 2);
    short* WT  = (short*)alloc((size_t)NOUT * DHID * 2);
    float* bc  = (float*)alloc((size_t)NOUT * 4);
    float* g   = (float*)alloc(128 * 4);

    // CSR build (same graph for all layers)
    zero_int_kernel<<<(N + 255) / 256, 256, 0, stream>>>(deg, N);
    zero_float_kernel<<<1, 128, 0, stream>>>(g, 128);
    count_kernel<<<(E + 255) / 256, 256, 0, stream>>>(dst, deg, E);
    scan_kernel<<<1, 256, 0, stream>>>(deg, offs, cnt, N, E);
    scatter_kernel<<<(E + 255) / 256, 256, 0, stream>>>(src, dst, offs, cnt, csr, E);

    // input -> bf16
    cvt_x_kernel<<<(N * FIN0 + 255) / 256, 256, 0, stream>>>(x, xb0, N * FIN0);

    int attn_blocks = (N + 3) / 4;   // 1 wave per node, 4 waves/block
    int comb_blocks = (N * DHID + 255) / 256;

    const short* xin = xb0;
    short* xouts[3] = { xb1, xb2, xb1 };
    for (int l = 0; l < 3; ++l) {
        int finShift = (l == 0) ? 6 : 7;
        int fin = 1 << finShift;
        const float* Wq = (const float*)d_in[2 + l * 8 + 0];
        const float* bq = (const float*)d_in[2 + l * 8 + 1];
        const float* Wk = (const float*)d_in[2 + l * 8 + 2];
        const float* bk = (const float*)d_in[2 + l * 8 + 3];
        const float* Wv = (const float*)d_in[2 + l * 8 + 4];
        const float* bv = (const float*)d_in[2 + l * 8 + 5];
        const float* Wss= (const float*)d_in[2 + l * 8 + 6];
        const float* bs = (const float*)d_in[2 + l * 8 + 7];

        cvt_w_kernel<<<(NOUT * fin + 255) / 256, 256, 0, stream>>>(
            Wq, Wk, Wv, Wss, bq, bk, bv, bs, WT, bc, finShift);

        dim3 ggrid((N + 63) / 64, NOUT / 64);
        gemm_qkvs_mfma<<<ggrid, 256, 0, stream>>>(xin, N, finShift, WT, bc, Q, Kb, Vb, S);
        attn_kernel<<<attn_blocks, 256, 0, stream>>>(Q, Kb, Vb, offs, csr, tmp, N);
        combine_kernel<<<comb_blocks, 256, 0, stream>>>(tmp, S, xouts[l], N);
        xin = xouts[l];
    }

    colsum_kernel<<<256, 128, 0, stream>>>(xb1, g, N);
    final_kernel<<<1, 128, 0, stream>>>(g, Wfc, bfc, (float*)d_out, 1.0f / N);
}

// Round 5
// 620.362 us; speedup vs baseline: 2.4712x; 1.3627x over previous
//
#include <hip/hip_runtime.h>
#include <hip/hip_bf16.h>
#include <math.h>

#define NNODES 25000
#define NEDGES 400000
#define FIN0 64
#define DHID 128
#define NHEAD 4
#define CDIM 128
#define HC (NHEAD * CDIM)   // 512
#define NOUT 1664           // Q512 | K512 | V512 | S128
#define SCALE 0.088388347648318447f  // 1/sqrt(128)

typedef __attribute__((ext_vector_type(8))) short short8;
typedef __attribute__((ext_vector_type(4))) float floatx4;
typedef __attribute__((ext_vector_type(2))) float fx2;

__device__ __forceinline__ short f2bf(float v) {
    unsigned u = __float_as_uint(v);
    u = (u + 0x7fffu + ((u >> 16) & 1u)) >> 16;   // RNE
    return (short)u;
}
__device__ __forceinline__ float bf2f(short s) {
    return __uint_as_float(((unsigned)(unsigned short)s) << 16);
}

// ---------------- utility kernels ----------------

__global__ void zero_int_kernel(int* __restrict__ p, int n) {
    int i = blockIdx.x * blockDim.x + threadIdx.x;
    if (i < n) p[i] = 0;
}

__global__ void zero_float_kernel(float* __restrict__ p, int n) {
    int i = blockIdx.x * blockDim.x + threadIdx.x;
    if (i < n) p[i] = 0.f;
}

__global__ void cvt_x_kernel(const float* __restrict__ x, short* __restrict__ xb, int total) {
    int i = blockIdx.x * blockDim.x + threadIdx.x;
    if (i < total) xb[i] = f2bf(x[i]);
}

// Build WcatT[1664][fin] (bf16, transposed) + bcat[1664] (fp32).
__global__ void cvt_w_kernel(const float* __restrict__ Wq, const float* __restrict__ Wk,
                             const float* __restrict__ Wv, const float* __restrict__ Ws,
                             const float* __restrict__ bq, const float* __restrict__ bk,
                             const float* __restrict__ bv, const float* __restrict__ bs,
                             short* __restrict__ WT, float* __restrict__ bc, int finShift) {
    int idx = blockIdx.x * blockDim.x + threadIdx.x;
    int fin = 1 << finShift;
    int total = NOUT << finShift;
    if (idx < total) {
        int c = idx >> finShift;
        int k = idx & (fin - 1);
        float v;
        if (c < 512)       v = Wq[k * 512 + c];
        else if (c < 1024) v = Wk[k * 512 + c - 512];
        else if (c < 1536) v = Wv[k * 512 + c - 1024];
        else               v = Ws[k * 128 + c - 1536];
        WT[idx] = f2bf(v);
    }
    if (idx < NOUT) {
        int c = idx;
        float b;
        if (c < 512)       b = bq[c];
        else if (c < 1024) b = bk[c - 512];
        else if (c < 1536) b = bv[c - 1024];
        else               b = bs[c - 1536];
        bc[c] = b;
    }
}

// ---------------- CSR build ----------------

__global__ void count_kernel(const int* __restrict__ dst, int* __restrict__ deg, int e) {
    int i = blockIdx.x * blockDim.x + threadIdx.x;
    if (i < e) atomicAdd(&deg[dst[i]], 1);
}

__global__ void scan_kernel(const int* __restrict__ deg, int* __restrict__ offs,
                            int* __restrict__ cnt, int n, int total) {
    __shared__ int sums[256];
    int t = threadIdx.x;
    int chunk = (n + 255) / 256;
    int b = t * chunk;
    int e = min(b + chunk, n);
    int s = 0;
    for (int i = b; i < e; ++i) s += deg[i];
    sums[t] = s;
    __syncthreads();
    for (int o = 1; o < 256; o <<= 1) {
        int v = (t >= o) ? sums[t - o] : 0;
        __syncthreads();
        sums[t] += v;
        __syncthreads();
    }
    int run = sums[t] - s;
    for (int i = b; i < e; ++i) {
        offs[i] = run;
        run += deg[i];
        cnt[i] = 0;
    }
    if (t == 0) offs[n] = total;
}

__global__ void scatter_kernel(const int* __restrict__ src, const int* __restrict__ dst,
                               const int* __restrict__ offs, int* __restrict__ cnt,
                               int* __restrict__ csr, int e) {
    int i = blockIdx.x * blockDim.x + threadIdx.x;
    if (i < e) {
        int d = dst[i];
        int pos = offs[d] + atomicAdd(&cnt[d], 1);
        csr[pos] = src[i];
    }
}

// ---------------- fused QKVS GEMM (bf16 MFMA) ----------------
// C = Xb[n x fin] @ Wcat[fin x 1664] + bcat.  Tile 64x64, 4 waves of 32x32.
// Out: [0,512) -> Qb bf16; [512,1024) -> KV fp8 (K half);
//      [1024,1536) -> KV fp8 (V half, +512 offset); [1536,1664) -> S fp32.
__global__ __launch_bounds__(256) void gemm_qkvs_mfma(
    const short* __restrict__ Xb, int n, int finShift,
    const short* __restrict__ WT, const float* __restrict__ bc,
    short* __restrict__ Qb, unsigned char* __restrict__ KV,
    float* __restrict__ S)
{
    __shared__ short Xs[64][136];
    __shared__ short Wt[64][136];

    int t = threadIdx.x;
    int row0 = blockIdx.x * 64, col0 = blockIdx.y * 64;
    int fin = 1 << finShift;
    int cs = finShift - 3;
    int cmask = (1 << cs) - 1;

    for (int i = t; i < (64 << cs); i += 256) {
        int r = i >> cs, c = (i & cmask) * 8;
        int gr = row0 + r;
        uint4 v = make_uint4(0u, 0u, 0u, 0u);
        if (gr < n) v = *(const uint4*)&Xb[(size_t)gr * fin + c];
        *(uint4*)&Xs[r][c] = v;
    }
    for (int i = t; i < (64 << cs); i += 256) {
        int r = i >> cs, c = (i & cmask) * 8;
        *(uint4*)&Wt[r][c] = *(const uint4*)&WT[((size_t)(col0 + r) << finShift) + c];
    }
    __syncthreads();

    int l = t & 63, w = t >> 6;
    int wr = (w >> 1) * 32, wc = (w & 1) * 32;
    int lr = l & 15, lk = (l >> 4) * 8;

    floatx4 acc[2][2] = {};
    for (int k0 = 0; k0 < fin; k0 += 32) {
        short8 a0 = *(const short8*)&Xs[wr + lr][k0 + lk];
        short8 a1 = *(const short8*)&Xs[wr + 16 + lr][k0 + lk];
        short8 b0 = *(const short8*)&Wt[wc + lr][k0 + lk];
        short8 b1 = *(const short8*)&Wt[wc + 16 + lr][k0 + lk];
        acc[0][0] = __builtin_amdgcn_mfma_f32_16x16x32_bf16(a0, b0, acc[0][0], 0, 0, 0);
        acc[0][1] = __builtin_amdgcn_mfma_f32_16x16x32_bf16(a0, b1, acc[0][1], 0, 0, 0);
        acc[1][0] = __builtin_amdgcn_mfma_f32_16x16x32_bf16(a1, b0, acc[1][0], 0, 0, 0);
        acc[1][1] = __builtin_amdgcn_mfma_f32_16x16x32_bf16(a1, b1, acc[1][1], 0, 0, 0);
    }

    int rb = (l >> 4) * 4;
    int cl = l & 15;
#pragma unroll
    for (int mi = 0; mi < 2; ++mi) {
#pragma unroll
        for (int ni = 0; ni < 2; ++ni) {
            int gc = col0 + wc + ni * 16 + cl;
            float bias = bc[gc];
#pragma unroll
            for (int r = 0; r < 4; ++r) {
                int gr = row0 + wr + mi * 16 + rb + r;
                if (gr < n) {
                    float v = acc[mi][ni][r] + bias;
                    if (gc < 512) {
                        Qb[(size_t)gr * 512 + gc] = f2bf(v);
                    } else if (gc < 1536) {
                        int idx = (gc < 1024) ? (gc - 512) : (512 + gc - 1024);
                        unsigned enc = (unsigned)__builtin_amdgcn_cvt_pk_fp8_f32(v, v, 0, false);
                        KV[(size_t)gr * 1024 + idx] = (unsigned char)enc;
                    } else {
                        S[(size_t)gr * 128 + gc - 1536] = v;
                    }
                }
            }
        }
    }
}

// ---------------- fused attention + head-mean + skip + relu ----------------
// One wave per dst node, all 4 heads. Lane i owns channels [8i,8i+8) of the
// 512-wide rows (head = lane>>4). K/V are fp8 e4m3, interleaved per node:
// KV[node][0..511] = K, KV[node][512..1023] = V.

__device__ __forceinline__ void unpack8(uint4 r, float* f) {
    f[0] = __uint_as_float(r.x << 16);
    f[1] = __uint_as_float(r.x & 0xffff0000u);
    f[2] = __uint_as_float(r.y << 16);
    f[3] = __uint_as_float(r.y & 0xffff0000u);
    f[4] = __uint_as_float(r.z << 16);
    f[5] = __uint_as_float(r.z & 0xffff0000u);
    f[6] = __uint_as_float(r.w << 16);
    f[7] = __uint_as_float(r.w & 0xffff0000u);
}

__device__ __forceinline__ void decf8(uint2 r, float* f) {
    fx2 a = __builtin_amdgcn_cvt_pk_f32_fp8(r.x, false);
    fx2 b = __builtin_amdgcn_cvt_pk_f32_fp8(r.x, true);
    fx2 c = __builtin_amdgcn_cvt_pk_f32_fp8(r.y, false);
    fx2 d = __builtin_amdgcn_cvt_pk_f32_fp8(r.y, true);
    f[0] = a[0]; f[1] = a[1]; f[2] = b[0]; f[3] = b[1];
    f[4] = c[0]; f[5] = c[1]; f[6] = d[0]; f[7] = d[1];
}

__device__ __forceinline__ float dotf8(const float* q, uint2 r) {
    float f[8];
    decf8(r, f);
    float p = 0.f;
#pragma unroll
    for (int j = 0; j < 8; ++j) p = fmaf(q[j], f[j], p);
    return p;
}

__device__ __forceinline__ void updf8(float& m, float& d, float* acc,
                                      float alpha, uint2 vr) {
    float vf[8];
    decf8(vr, vf);
    float nm = fmaxf(m, alpha);
    float sc = __expf(m - nm);    // first iter: exp(-inf)=0
    float w  = __expf(alpha - nm);
    d = d * sc + w;
#pragma unroll
    for (int j = 0; j < 8; ++j) acc[j] = acc[j] * sc + w * vf[j];
    m = nm;
}

__global__ __launch_bounds__(256) void attn_kernel(
    const short* __restrict__ Qb, const unsigned char* __restrict__ KV,
    const int* __restrict__ offs, const int* __restrict__ csr,
    const float* __restrict__ S, short* __restrict__ Xo, int n)
{
    int node = (blockIdx.x * blockDim.x + threadIdx.x) >> 6;
    if (node >= n) return;
    int lane = threadIdx.x & 63;

    float qf[8];
    {
        uint4 qr = *(const uint4*)&Qb[(size_t)node * 512 + lane * 8];
        unpack8(qr, qf);
    }

    int beg = offs[node], end = offs[node + 1];
    float m = -INFINITY, d = 0.f;
    float acc[8] = {};

    int e = beg;
    for (; e + 3 < end; e += 4) {
        int s0 = csr[e], s1 = csr[e + 1], s2 = csr[e + 2], s3 = csr[e + 3];
        const unsigned char* b0 = KV + (size_t)s0 * 1024 + lane * 8;
        const unsigned char* b1 = KV + (size_t)s1 * 1024 + lane * 8;
        const unsigned char* b2 = KV + (size_t)s2 * 1024 + lane * 8;
        const unsigned char* b3 = KV + (size_t)s3 * 1024 + lane * 8;
        uint2 k0 = *(const uint2*)b0;
        uint2 k1 = *(const uint2*)b1;
        uint2 k2 = *(const uint2*)b2;
        uint2 k3 = *(const uint2*)b3;
        uint2 v0 = *(const uint2*)(b0 + 512);
        uint2 v1 = *(const uint2*)(b1 + 512);
        uint2 v2 = *(const uint2*)(b2 + 512);
        uint2 v3 = *(const uint2*)(b3 + 512);
        float p0 = dotf8(qf, k0);
        float p1 = dotf8(qf, k1);
        float p2 = dotf8(qf, k2);
        float p3 = dotf8(qf, k3);
#pragma unroll
        for (int o = 1; o < 16; o <<= 1) {
            p0 += __shfl_xor(p0, o);
            p1 += __shfl_xor(p1, o);
            p2 += __shfl_xor(p2, o);
            p3 += __shfl_xor(p3, o);
        }
        updf8(m, d, acc, p0 * SCALE, v0);
        updf8(m, d, acc, p1 * SCALE, v1);
        updf8(m, d, acc, p2 * SCALE, v2);
        updf8(m, d, acc, p3 * SCALE, v3);
    }
    for (; e < end; ++e) {
        int s0 = csr[e];
        const unsigned char* b0 = KV + (size_t)s0 * 1024 + lane * 8;
        uint2 k0 = *(const uint2*)b0;
        uint2 v0 = *(const uint2*)(b0 + 512);
        float p0 = dotf8(qf, k0);
#pragma unroll
        for (int o = 1; o < 16; o <<= 1) p0 += __shfl_xor(p0, o);
        updf8(m, d, acc, p0 * SCALE, v0);
    }

    float inv = (d > 0.f) ? 1.f / d : 0.f;
#pragma unroll
    for (int j = 0; j < 8; ++j) acc[j] *= inv;

    // head mean across the 4 heads (lanes l, l^16, l^32, l^48 share channel)
#pragma unroll
    for (int j = 0; j < 8; ++j) {
        acc[j] += __shfl_xor(acc[j], 16);
        acc[j] += __shfl_xor(acc[j], 32);
    }

    if (lane < 16) {
        int c0 = lane * 8;
        const float* Srow = S + (size_t)node * 128 + c0;
        short8 o;
#pragma unroll
        for (int j = 0; j < 8; ++j)
            o[j] = f2bf(fmaxf(acc[j] * 0.25f + Srow[j], 0.f));
        *(short8*)&Xo[(size_t)node * 128 + c0] = o;
    }
}

// ---------------- column sum + final sigmoid ----------------
__global__ void colsum_kernel(const short* __restrict__ X, float* __restrict__ g, int n) {
    int c = threadIdx.x;  // 128 threads
    int rpb = (n + gridDim.x - 1) / gridDim.x;
    int r0 = blockIdx.x * rpb;
    int r1 = min(r0 + rpb, n);
    float acc = 0.f;
    for (int r = r0; r < r1; ++r) acc += bf2f(X[r * DHID + c]);
    atomicAdd(&g[c], acc);
}

__global__ void final_kernel(const float* __restrict__ g, const float* __restrict__ Wfc,
                             const float* __restrict__ bfc, float* __restrict__ out, float invn) {
    __shared__ float red[128];
    int t = threadIdx.x;
    red[t] = g[t] * invn * Wfc[t];
    __syncthreads();
    for (int o = 64; o > 0; o >>= 1) {
        if (t < o) red[t] += red[t + o];
        __syncthreads();
    }
    if (t == 0) {
        float z = red[0] + bfc[0];
        out[0] = 1.f / (1.f + expf(-z));
    }
}

// ---------------- host ----------------

extern "C" void kernel_launch(void* const* d_in, const int* in_sizes, int n_in,
                              void* d_out, int out_size, void* d_ws, size_t ws_size,
                              hipStream_t stream) {
    const int N = NNODES, E = NEDGES;
    const float* x = (const float*)d_in[0];
    const int* ei = (const int*)d_in[1];
    const int* src = ei;
    const int* dst = ei + E;
    const float* Wfc = (const float*)d_in[26];
    const float* bfc = (const float*)d_in[27];

    size_t off = 0;
    auto alloc = [&](size_t bytes) -> char* {
        char* p = (char*)d_ws + off;
        off += (bytes + 255) & ~(size_t)255;
        return p;
    };
    int* deg   = (int*)alloc((size_t)N * 4);
    int* cnt   = (int*)alloc((size_t)N * 4);
    int* offs  = (int*)alloc((size_t)(N + 1) * 4);
    int* csr   = (int*)alloc((size_t)E * 4);
    short* Qb  = (short*)alloc((size_t)N * HC * 2);
    unsigned char* KV = (unsigned char*)alloc((size_t)N * 1024);
    float* S   = (float*)alloc((size_t)N * DHID * 4);
    short* xb0 = (short*)alloc((size_t)N * FIN0 * 2);
    short* xb1 = (short*)alloc((size_t)N * DHID * 2);
    short* xb2 = (short*)alloc((size_t)N * DHID * 2);
    short* WT  = (short*)alloc((size_t)NOUT * DHID * 2);
    float* bc  = (float*)alloc((size_t)NOUT * 4);
    float* g   = (float*)alloc(128 * 4);

    // CSR build (same graph for all layers)
    zero_int_kernel<<<(N + 255) / 256, 256, 0, stream>>>(deg, N);
    zero_float_kernel<<<1, 128, 0, stream>>>(g, 128);
    count_kernel<<<(E + 255) / 256, 256, 0, stream>>>(dst, deg, E);
    scan_kernel<<<1, 256, 0, stream>>>(deg, offs, cnt, N, E);
    scatter_kernel<<<(E + 255) / 256, 256, 0, stream>>>(src, dst, offs, cnt, csr, E);

    // input -> bf16
    cvt_x_kernel<<<(N * FIN0 + 255) / 256, 256, 0, stream>>>(x, xb0, N * FIN0);

    int attn_blocks = (N + 3) / 4;   // 1 wave per node, 4 waves/block

    const short* xin = xb0;
    short* xouts[3] = { xb1, xb2, xb1 };
    for (int l = 0; l < 3; ++l) {
        int finShift = (l == 0) ? 6 : 7;
        int fin = 1 << finShift;
        const float* Wq = (const float*)d_in[2 + l * 8 + 0];
        const float* bq = (const float*)d_in[2 + l * 8 + 1];
        const float* Wk = (const float*)d_in[2 + l * 8 + 2];
        const float* bk = (const float*)d_in[2 + l * 8 + 3];
        const float* Wv = (const float*)d_in[2 + l * 8 + 4];
        const float* bv = (const float*)d_in[2 + l * 8 + 5];
        const float* Wss= (const float*)d_in[2 + l * 8 + 6];
        const float* bs = (const float*)d_in[2 + l * 8 + 7];

        cvt_w_kernel<<<(NOUT * fin + 255) / 256, 256, 0, stream>>>(
            Wq, Wk, Wv, Wss, bq, bk, bv, bs, WT, bc, finShift);

        dim3 ggrid((N + 63) / 64, NOUT / 64);
        gemm_qkvs_mfma<<<ggrid, 256, 0, stream>>>(xin, N, finShift, WT, bc, Qb, KV, S);
        attn_kernel<<<attn_blocks, 256, 0, stream>>>(Qb, KV, offs, csr, S, xouts[l], N);
        xin = xouts[l];
    }

    colsum_kernel<<<256, 128, 0, stream>>>(xb1, g, N);
    final_kernel<<<1, 128, 0, stream>>>(g, Wfc, bfc, (float*)d_out, 1.0f / N);
}

// Round 6
// 609.467 us; speedup vs baseline: 2.5154x; 1.0179x over previous
//
#include <hip/hip_runtime.h>
#include <hip/hip_bf16.h>
#include <math.h>

#define NNODES 25000
#define NEDGES 400000
#define FIN0 64
#define DHID 128
#define NHEAD 4
#define CDIM 128
#define HC (NHEAD * CDIM)   // 512
#define NOUT 1664           // Q512 | K512 | V512 | S128
#define SCALE 0.088388347648318447f  // 1/sqrt(128)

typedef __attribute__((ext_vector_type(8))) short short8;
typedef __attribute__((ext_vector_type(4))) float floatx4;
typedef __attribute__((ext_vector_type(2))) float fx2;

__device__ __forceinline__ short f2bf(float v) {
    unsigned u = __float_as_uint(v);
    u = (u + 0x7fffu + ((u >> 16) & 1u)) >> 16;   // RNE
    return (short)u;
}
__device__ __forceinline__ float bf2f(short s) {
    return __uint_as_float(((unsigned)(unsigned short)s) << 16);
}

// ---------------- utility kernels ----------------

__global__ void zero_int_kernel(int* __restrict__ p, int n) {
    int i = blockIdx.x * blockDim.x + threadIdx.x;
    if (i < n) p[i] = 0;
}

__global__ void zero_float_kernel(float* __restrict__ p, int n) {
    int i = blockIdx.x * blockDim.x + threadIdx.x;
    if (i < n) p[i] = 0.f;
}

__global__ void cvt_x_kernel(const float* __restrict__ x, short* __restrict__ xb, int total) {
    int i = blockIdx.x * blockDim.x + threadIdx.x;
    if (i < total) xb[i] = f2bf(x[i]);
}

// Build WcatT[1664][fin] (bf16, transposed) + bcat[1664] (fp32).
__global__ void cvt_w_kernel(const float* __restrict__ Wq, const float* __restrict__ Wk,
                             const float* __restrict__ Wv, const float* __restrict__ Ws,
                             const float* __restrict__ bq, const float* __restrict__ bk,
                             const float* __restrict__ bv, const float* __restrict__ bs,
                             short* __restrict__ WT, float* __restrict__ bc, int finShift) {
    int idx = blockIdx.x * blockDim.x + threadIdx.x;
    int fin = 1 << finShift;
    int total = NOUT << finShift;
    if (idx < total) {
        int c = idx >> finShift;
        int k = idx & (fin - 1);
        float v;
        if (c < 512)       v = Wq[k * 512 + c];
        else if (c < 1024) v = Wk[k * 512 + c - 512];
        else if (c < 1536) v = Wv[k * 512 + c - 1024];
        else               v = Ws[k * 128 + c - 1536];
        WT[idx] = f2bf(v);
    }
    if (idx < NOUT) {
        int c = idx;
        float b;
        if (c < 512)       b = bq[c];
        else if (c < 1024) b = bk[c - 512];
        else if (c < 1536) b = bv[c - 1024];
        else               b = bs[c - 1536];
        bc[c] = b;
    }
}

// ---------------- CSR build ----------------

__global__ void count_kernel(const int* __restrict__ dst, int* __restrict__ deg, int e) {
    int i = blockIdx.x * blockDim.x + threadIdx.x;
    if (i < e) atomicAdd(&deg[dst[i]], 1);
}

__global__ void scan_kernel(const int* __restrict__ deg, int* __restrict__ offs,
                            int* __restrict__ cnt, int n, int total) {
    __shared__ int sums[256];
    int t = threadIdx.x;
    int chunk = (n + 255) / 256;
    int b = t * chunk;
    int e = min(b + chunk, n);
    int s = 0;
    for (int i = b; i < e; ++i) s += deg[i];
    sums[t] = s;
    __syncthreads();
    for (int o = 1; o < 256; o <<= 1) {
        int v = (t >= o) ? sums[t - o] : 0;
        __syncthreads();
        sums[t] += v;
        __syncthreads();
    }
    int run = sums[t] - s;
    for (int i = b; i < e; ++i) {
        offs[i] = run;
        run += deg[i];
        cnt[i] = 0;
    }
    if (t == 0) offs[n] = total;
}

__global__ void scatter_kernel(const int* __restrict__ src, const int* __restrict__ dst,
                               const int* __restrict__ offs, int* __restrict__ cnt,
                               int* __restrict__ csr, int e) {
    int i = blockIdx.x * blockDim.x + threadIdx.x;
    if (i < e) {
        int d = dst[i];
        int pos = offs[d] + atomicAdd(&cnt[d], 1);
        csr[pos] = src[i];
    }
}

// ---------------- fused QKVS GEMM (bf16 MFMA, 128x128 tiles) ----------------
// C = Xb[n x FIN] @ Wcat[FIN x 1664] + bcat.  4 waves, each 64x64 (4x4 MFMA tiles).
// blockIdx.y: 0-3 -> Q bf16, 4-7 -> K fp8, 8-11 -> V fp8, 12 -> S bf16.
template<int FIN>
__global__ __launch_bounds__(256) void gemm_qkvs_mfma(
    const short* __restrict__ Xb, int n,
    const short* __restrict__ WT, const float* __restrict__ bc,
    short* __restrict__ Qb, unsigned char* __restrict__ KV,
    short* __restrict__ Sb)
{
    constexpr int PITCH = FIN + 8;
    constexpr int CSH = (FIN == 128) ? 4 : 3;   // log2(FIN/8)
    constexpr int CMASK = (1 << CSH) - 1;

    __shared__ short Xs[128][PITCH];
    __shared__ short Wt[128][PITCH];

    int t = threadIdx.x;
    int row0 = blockIdx.x * 128;
    int y = blockIdx.y;
    int col0 = y * 128;

    for (int i = t; i < (128 << CSH); i += 256) {
        int r = i >> CSH, c = (i & CMASK) * 8;
        int gr = row0 + r;
        uint4 v = make_uint4(0u, 0u, 0u, 0u);
        if (gr < n) v = *(const uint4*)&Xb[(size_t)gr * FIN + c];
        *(uint4*)&Xs[r][c] = v;
    }
    for (int i = t; i < (128 << CSH); i += 256) {
        int r = i >> CSH, c = (i & CMASK) * 8;
        *(uint4*)&Wt[r][c] = *(const uint4*)&WT[(size_t)(col0 + r) * FIN + c];
    }
    __syncthreads();

    int l = t & 63, w = t >> 6;
    int wr = (w >> 1) * 64, wc = (w & 1) * 64;
    int lr = l & 15, lk = (l >> 4) * 8;

    floatx4 acc[4][4] = {};
    for (int k0 = 0; k0 < FIN; k0 += 32) {
        short8 a[4], b[4];
#pragma unroll
        for (int mi = 0; mi < 4; ++mi)
            a[mi] = *(const short8*)&Xs[wr + mi * 16 + lr][k0 + lk];
#pragma unroll
        for (int ni = 0; ni < 4; ++ni)
            b[ni] = *(const short8*)&Wt[wc + ni * 16 + lr][k0 + lk];
#pragma unroll
        for (int mi = 0; mi < 4; ++mi)
#pragma unroll
            for (int ni = 0; ni < 4; ++ni)
                acc[mi][ni] = __builtin_amdgcn_mfma_f32_16x16x32_bf16(
                    a[mi], b[ni], acc[mi][ni], 0, 0, 0);
    }

    int rb = (l >> 4) * 4, cl = l & 15;
    int kind = (y < 4) ? 0 : (y < 8) ? 1 : (y < 12) ? 2 : 3;
#pragma unroll
    for (int mi = 0; mi < 4; ++mi) {
#pragma unroll
        for (int ni = 0; ni < 4; ++ni) {
            int gc = col0 + wc + ni * 16 + cl;
            float bias = bc[gc];
#pragma unroll
            for (int r = 0; r < 4; ++r) {
                int gr = row0 + wr + mi * 16 + rb + r;
                if (gr >= n) continue;
                float v = acc[mi][ni][r] + bias;
                if (kind == 0) {
                    Qb[(size_t)gr * 512 + gc] = f2bf(v);
                } else if (kind == 1) {
                    unsigned enc = (unsigned)__builtin_amdgcn_cvt_pk_fp8_f32(v, v, 0, false);
                    KV[(size_t)gr * 1024 + (gc - 512)] = (unsigned char)enc;
                } else if (kind == 2) {
                    unsigned enc = (unsigned)__builtin_amdgcn_cvt_pk_fp8_f32(v, v, 0, false);
                    KV[(size_t)gr * 1024 + 512 + (gc - 1024)] = (unsigned char)enc;
                } else {
                    Sb[(size_t)gr * 128 + (gc - 1536)] = f2bf(v);
                }
            }
        }
    }
}

// ---------------- fused attention + head-mean + skip + relu ----------------
// One wave per dst node, all 4 heads. Lane i owns channels [8i,8i+8) of the
// 512-wide rows (head = lane>>4). K/V are fp8 e4m3, interleaved per node:
// KV[node][0..511] = K, KV[node][512..1023] = V.

__device__ __forceinline__ void unpack8(uint4 r, float* f) {
    f[0] = __uint_as_float(r.x << 16);
    f[1] = __uint_as_float(r.x & 0xffff0000u);
    f[2] = __uint_as_float(r.y << 16);
    f[3] = __uint_as_float(r.y & 0xffff0000u);
    f[4] = __uint_as_float(r.z << 16);
    f[5] = __uint_as_float(r.z & 0xffff0000u);
    f[6] = __uint_as_float(r.w << 16);
    f[7] = __uint_as_float(r.w & 0xffff0000u);
}

__device__ __forceinline__ void decf8(uint2 r, float* f) {
    fx2 a = __builtin_amdgcn_cvt_pk_f32_fp8(r.x, false);
    fx2 b = __builtin_amdgcn_cvt_pk_f32_fp8(r.x, true);
    fx2 c = __builtin_amdgcn_cvt_pk_f32_fp8(r.y, false);
    fx2 d = __builtin_amdgcn_cvt_pk_f32_fp8(r.y, true);
    f[0] = a[0]; f[1] = a[1]; f[2] = b[0]; f[3] = b[1];
    f[4] = c[0]; f[5] = c[1]; f[6] = d[0]; f[7] = d[1];
}

__device__ __forceinline__ float dotf8(const float* q, uint2 r) {
    float f[8];
    decf8(r, f);
    float p = 0.f;
#pragma unroll
    for (int j = 0; j < 8; ++j) p = fmaf(q[j], f[j], p);
    return p;
}

__device__ __forceinline__ void updf8(float& m, float& d, float* acc,
                                      float alpha, uint2 vr) {
    float vf[8];
    decf8(vr, vf);
    float nm = fmaxf(m, alpha);
    float sc = __expf(m - nm);    // first iter: exp(-inf)=0
    float w  = __expf(alpha - nm);
    d = d * sc + w;
#pragma unroll
    for (int j = 0; j < 8; ++j) acc[j] = acc[j] * sc + w * vf[j];
    m = nm;
}

__global__ __launch_bounds__(256) void attn_kernel(
    const short* __restrict__ Qb, const unsigned char* __restrict__ KV,
    const int* __restrict__ offs, const int* __restrict__ csr,
    const short* __restrict__ Sb, short* __restrict__ Xo, int n)
{
    int node = (blockIdx.x * blockDim.x + threadIdx.x) >> 6;
    if (node >= n) return;
    int lane = threadIdx.x & 63;

    float qf[8];
    {
        uint4 qr = *(const uint4*)&Qb[(size_t)node * 512 + lane * 8];
        unpack8(qr, qf);
    }

    int beg = offs[node], end = offs[node + 1];
    float m = -INFINITY, d = 0.f;
    float acc[8] = {};

    int e = beg;
    for (; e + 3 < end; e += 4) {
        int s0 = csr[e], s1 = csr[e + 1], s2 = csr[e + 2], s3 = csr[e + 3];
        const unsigned char* b0 = KV + (size_t)s0 * 1024 + lane * 8;
        const unsigned char* b1 = KV + (size_t)s1 * 1024 + lane * 8;
        const unsigned char* b2 = KV + (size_t)s2 * 1024 + lane * 8;
        const unsigned char* b3 = KV + (size_t)s3 * 1024 + lane * 8;
        uint2 k0 = *(const uint2*)b0;
        uint2 k1 = *(const uint2*)b1;
        uint2 k2 = *(const uint2*)b2;
        uint2 k3 = *(const uint2*)b3;
        uint2 v0 = *(const uint2*)(b0 + 512);
        uint2 v1 = *(const uint2*)(b1 + 512);
        uint2 v2 = *(const uint2*)(b2 + 512);
        uint2 v3 = *(const uint2*)(b3 + 512);
        float p0 = dotf8(qf, k0);
        float p1 = dotf8(qf, k1);
        float p2 = dotf8(qf, k2);
        float p3 = dotf8(qf, k3);
#pragma unroll
        for (int o = 1; o < 16; o <<= 1) {
            p0 += __shfl_xor(p0, o);
            p1 += __shfl_xor(p1, o);
            p2 += __shfl_xor(p2, o);
            p3 += __shfl_xor(p3, o);
        }
        updf8(m, d, acc, p0 * SCALE, v0);
        updf8(m, d, acc, p1 * SCALE, v1);
        updf8(m, d, acc, p2 * SCALE, v2);
        updf8(m, d, acc, p3 * SCALE, v3);
    }
    for (; e < end; ++e) {
        int s0 = csr[e];
        const unsigned char* b0 = KV + (size_t)s0 * 1024 + lane * 8;
        uint2 k0 = *(const uint2*)b0;
        uint2 v0 = *(const uint2*)(b0 + 512);
        float p0 = dotf8(qf, k0);
#pragma unroll
        for (int o = 1; o < 16; o <<= 1) p0 += __shfl_xor(p0, o);
        updf8(m, d, acc, p0 * SCALE, v0);
    }

    float inv = (d > 0.f) ? 1.f / d : 0.f;
#pragma unroll
    for (int j = 0; j < 8; ++j) acc[j] *= inv;

    // head mean across the 4 heads (lanes l, l^16, l^32, l^48 share channel)
#pragma unroll
    for (int j = 0; j < 8; ++j) {
        acc[j] += __shfl_xor(acc[j], 16);
        acc[j] += __shfl_xor(acc[j], 32);
    }

    if (lane < 16) {
        int c0 = lane * 8;
        float sf[8];
        uint4 sr = *(const uint4*)&Sb[(size_t)node * 128 + c0];
        unpack8(sr, sf);
        short8 o;
#pragma unroll
        for (int j = 0; j < 8; ++j)
            o[j] = f2bf(fmaxf(acc[j] * 0.25f + sf[j], 0.f));
        *(short8*)&Xo[(size_t)node * 128 + c0] = o;
    }
}

// ---------------- column sum + final sigmoid ----------------
__global__ void colsum_kernel(const short* __restrict__ X, float* __restrict__ g, int n) {
    int c = threadIdx.x;  // 128 threads
    int rpb = (n + gridDim.x - 1) / gridDim.x;
    int r0 = blockIdx.x * rpb;
    int r1 = min(r0 + rpb, n);
    float acc = 0.f;
    for (int r = r0; r < r1; ++r) acc += bf2f(X[r * DHID + c]);
    atomicAdd(&g[c], acc);
}

__global__ void final_kernel(const float* __restrict__ g, const float* __restrict__ Wfc,
                             const float* __restrict__ bfc, float* __restrict__ out, float invn) {
    __shared__ float red[128];
    int t = threadIdx.x;
    red[t] = g[t] * invn * Wfc[t];
    __syncthreads();
    for (int o = 64; o > 0; o >>= 1) {
        if (t < o) red[t] += red[t + o];
        __syncthreads();
    }
    if (t == 0) {
        float z = red[0] + bfc[0];
        out[0] = 1.f / (1.f + expf(-z));
    }
}

// ---------------- host ----------------

extern "C" void kernel_launch(void* const* d_in, const int* in_sizes, int n_in,
                              void* d_out, int out_size, void* d_ws, size_t ws_size,
                              hipStream_t stream) {
    const int N = NNODES, E = NEDGES;
    const float* x = (const float*)d_in[0];
    const int* ei = (const int*)d_in[1];
    const int* src = ei;
    const int* dst = ei + E;
    const float* Wfc = (const float*)d_in[26];
    const float* bfc = (const float*)d_in[27];

    size_t off = 0;
    auto alloc = [&](size_t bytes) -> char* {
        char* p = (char*)d_ws + off;
        off += (bytes + 255) & ~(size_t)255;
        return p;
    };
    int* deg   = (int*)alloc((size_t)N * 4);
    int* cnt   = (int*)alloc((size_t)N * 4);
    int* offs  = (int*)alloc((size_t)(N + 1) * 4);
    int* csr   = (int*)alloc((size_t)E * 4);
    short* Qb  = (short*)alloc((size_t)N * HC * 2);
    unsigned char* KV = (unsigned char*)alloc((size_t)N * 1024);
    short* Sb  = (short*)alloc((size_t)N * DHID * 2);
    short* xb0 = (short*)alloc((size_t)N * FIN0 * 2);
    short* xb1 = (short*)alloc((size_t)N * DHID * 2);
    short* xb2 = (short*)alloc((size_t)N * DHID * 2);
    short* WT  = (short*)alloc((size_t)NOUT * DHID * 2);
    float* bc  = (float*)alloc((size_t)NOUT * 4);
    float* g   = (float*)alloc(128 * 4);

    // CSR build (same graph for all layers)
    zero_int_kernel<<<(N + 255) / 256, 256, 0, stream>>>(deg, N);
    zero_float_kernel<<<1, 128, 0, stream>>>(g, 128);
    count_kernel<<<(E + 255) / 256, 256, 0, stream>>>(dst, deg, E);
    scan_kernel<<<1, 256, 0, stream>>>(deg, offs, cnt, N, E);
    scatter_kernel<<<(E + 255) / 256, 256, 0, stream>>>(src, dst, offs, cnt, csr, E);

    // input -> bf16
    cvt_x_kernel<<<(N * FIN0 + 255) / 256, 256, 0, stream>>>(x, xb0, N * FIN0);

    int attn_blocks = (N + 3) / 4;   // 1 wave per node, 4 waves/block

    const short* xin = xb0;
    short* xouts[3] = { xb1, xb2, xb1 };
    for (int l = 0; l < 3; ++l) {
        int finShift = (l == 0) ? 6 : 7;
        int fin = 1 << finShift;
        const float* Wq = (const float*)d_in[2 + l * 8 + 0];
        const float* bq = (const float*)d_in[2 + l * 8 + 1];
        const float* Wk = (const float*)d_in[2 + l * 8 + 2];
        const float* bk = (const float*)d_in[2 + l * 8 + 3];
        const float* Wv = (const float*)d_in[2 + l * 8 + 4];
        const float* bv = (const float*)d_in[2 + l * 8 + 5];
        const float* Wss= (const float*)d_in[2 + l * 8 + 6];
        const float* bs = (const float*)d_in[2 + l * 8 + 7];

        cvt_w_kernel<<<(NOUT * fin + 255) / 256, 256, 0, stream>>>(
            Wq, Wk, Wv, Wss, bq, bk, bv, bs, WT, bc, finShift);

        dim3 ggrid((N + 127) / 128, 13);
        if (l == 0)
            gemm_qkvs_mfma<64><<<ggrid, 256, 0, stream>>>(xin, N, WT, bc, Qb, KV, Sb);
        else
            gemm_qkvs_mfma<128><<<ggrid, 256, 0, stream>>>(xin, N, WT, bc, Qb, KV, Sb);
        attn_kernel<<<attn_blocks, 256, 0, stream>>>(Qb, KV, offs, csr, Sb, xouts[l], N);
        xin = xouts[l];
    }

    colsum_kernel<<<256, 128, 0, stream>>>(xb1, g, N);
    final_kernel<<<1, 128, 0, stream>>>(g, Wfc, bfc, (float*)d_out, 1.0f / N);
}

// Round 7
// 590.113 us; speedup vs baseline: 2.5979x; 1.0328x over previous
//
#include <hip/hip_runtime.h>
#include <hip/hip_bf16.h>
#include <math.h>

#define NNODES 25000
#define NEDGES 400000
#define FIN0 64
#define DHID 128
#define NHEAD 4
#define CDIM 128
#define HC (NHEAD * CDIM)   // 512
#define NOUT 1664           // Q512 | K512 | V512 | S128
#define SCALE 0.088388347648318447f  // 1/sqrt(128)

typedef __attribute__((ext_vector_type(8))) short short8;
typedef __attribute__((ext_vector_type(4))) float floatx4;
typedef __attribute__((ext_vector_type(2))) float fx2;

__device__ __forceinline__ short f2bf(float v) {
    unsigned u = __float_as_uint(v);
    u = (u + 0x7fffu + ((u >> 16) & 1u)) >> 16;   // RNE
    return (short)u;
}
__device__ __forceinline__ float bf2f(short s) {
    return __uint_as_float(((unsigned)(unsigned short)s) << 16);
}

// ---------------- utility kernels ----------------

__global__ void zero_ws_kernel(int* __restrict__ deg, float* __restrict__ g, int n) {
    int i = blockIdx.x * blockDim.x + threadIdx.x;
    if (i < n) deg[i] = 0;
    if (i < 128) g[i] = 0.f;
}

__global__ void cvt_x_kernel(const float* __restrict__ x, short* __restrict__ xb, int total) {
    int i = blockIdx.x * blockDim.x + threadIdx.x;
    if (i < total) xb[i] = f2bf(x[i]);
}

// Build WcatT[1664][fin] (bf16, transposed) + bcat[1664] (fp32).
__global__ void cvt_w_kernel(const float* __restrict__ Wq, const float* __restrict__ Wk,
                             const float* __restrict__ Wv, const float* __restrict__ Ws,
                             const float* __restrict__ bq, const float* __restrict__ bk,
                             const float* __restrict__ bv, const float* __restrict__ bs,
                             short* __restrict__ WT, float* __restrict__ bc, int finShift) {
    int idx = blockIdx.x * blockDim.x + threadIdx.x;
    int fin = 1 << finShift;
    int total = NOUT << finShift;
    if (idx < total) {
        int c = idx >> finShift;
        int k = idx & (fin - 1);
        float v;
        if (c < 512)       v = Wq[k * 512 + c];
        else if (c < 1024) v = Wk[k * 512 + c - 512];
        else if (c < 1536) v = Wv[k * 512 + c - 1024];
        else               v = Ws[k * 128 + c - 1536];
        WT[idx] = f2bf(v);
    }
    if (idx < NOUT) {
        int c = idx;
        float b;
        if (c < 512)       b = bq[c];
        else if (c < 1024) b = bk[c - 512];
        else if (c < 1536) b = bv[c - 1024];
        else               b = bs[c - 1536];
        bc[c] = b;
    }
}

// ---------------- CSR build ----------------

__global__ void count_kernel(const int* __restrict__ dst, int* __restrict__ deg, int e) {
    int i = blockIdx.x * blockDim.x + threadIdx.x;
    if (i < e) atomicAdd(&deg[dst[i]], 1);
}

__global__ void scan_kernel(const int* __restrict__ deg, int* __restrict__ offs,
                            int* __restrict__ cnt, int n, int total) {
    __shared__ int sums[256];
    int t = threadIdx.x;
    int chunk = (n + 255) / 256;
    int b = t * chunk;
    int e = min(b + chunk, n);
    int s = 0;
    for (int i = b; i < e; ++i) s += deg[i];
    sums[t] = s;
    __syncthreads();
    for (int o = 1; o < 256; o <<= 1) {
        int v = (t >= o) ? sums[t - o] : 0;
        __syncthreads();
        sums[t] += v;
        __syncthreads();
    }
    int run = sums[t] - s;
    for (int i = b; i < e; ++i) {
        offs[i] = run;
        run += deg[i];
        cnt[i] = 0;
    }
    if (t == 0) offs[n] = total;
}

__global__ void scatter_kernel(const int* __restrict__ src, const int* __restrict__ dst,
                               const int* __restrict__ offs, int* __restrict__ cnt,
                               int* __restrict__ csr, int e) {
    int i = blockIdx.x * blockDim.x + threadIdx.x;
    if (i < e) {
        int d = dst[i];
        int pos = offs[d] + atomicAdd(&cnt[d], 1);
        csr[pos] = src[i];
    }
}

// ---------------- fused QKVS GEMM (bf16 MFMA) ----------------
// C = Xb[n x FIN] @ Wcat[FIN x 1664] + bcat.
// Block: 64 rows x 256 cols, 4 waves; each wave one 64x64 slice (4x4 frags).
// X staged in LDS; W fragments read DIRECT from global (L2-resident, 426 KB).
// blockIdx.y*256 -> col0: 0,256=Q | 512,768=K | 1024,1280=V | 1536=S(128, 2 waves idle)
template<int FIN>
__global__ __launch_bounds__(256) void gemm_qkvs_mfma(
    const short* __restrict__ Xb, int n,
    const short* __restrict__ WT, const float* __restrict__ bc,
    short* __restrict__ Qb, unsigned char* __restrict__ KV,
    short* __restrict__ Sb)
{
    constexpr int PITCH = FIN + 8;
    constexpr int CPR = FIN / 8;            // uint4 chunks per row
    __shared__ short Xs[64][PITCH];

    int t = threadIdx.x;
    int row0 = blockIdx.x * 64;
    int col0 = blockIdx.y * 256;

    for (int i = t; i < 64 * CPR; i += 256) {
        int r = i / CPR, c = (i % CPR) * 8;
        int gr = row0 + r;
        uint4 v = make_uint4(0u, 0u, 0u, 0u);
        if (gr < n) v = *(const uint4*)&Xb[(size_t)gr * FIN + c];
        *(uint4*)&Xs[r][c] = v;
    }
    __syncthreads();

    int l = t & 63, w = t >> 6;
    int wcol = col0 + w * 64;
    if (wcol >= NOUT) return;            // S block: waves 2,3 idle (after barrier)
    int lr = l & 15, lk = (l >> 4) * 8;
    int cl = l & 15, rb = (l >> 4) * 4;

    // prefetch bias (4 floats/thread)
    float bias[4];
#pragma unroll
    for (int ni = 0; ni < 4; ++ni) bias[ni] = bc[wcol + ni * 16 + cl];

    floatx4 acc[4][4] = {};
    for (int k0 = 0; k0 < FIN; k0 += 32) {
        short8 b[4];
#pragma unroll
        for (int ni = 0; ni < 4; ++ni)
            b[ni] = *(const short8*)&WT[(size_t)(wcol + ni * 16 + lr) * FIN + k0 + lk];
        short8 a[4];
#pragma unroll
        for (int mi = 0; mi < 4; ++mi)
            a[mi] = *(const short8*)&Xs[mi * 16 + lr][k0 + lk];
#pragma unroll
        for (int mi = 0; mi < 4; ++mi)
#pragma unroll
            for (int ni = 0; ni < 4; ++ni)
                acc[mi][ni] = __builtin_amdgcn_mfma_f32_16x16x32_bf16(
                    a[mi], b[ni], acc[mi][ni], 0, 0, 0);
    }

    int kind = (wcol < 512) ? 0 : (wcol < 1024) ? 1 : (wcol < 1536) ? 2 : 3;
#pragma unroll
    for (int mi = 0; mi < 4; ++mi) {
#pragma unroll
        for (int ni = 0; ni < 4; ++ni) {
            int gc = wcol + ni * 16 + cl;
#pragma unroll
            for (int r = 0; r < 4; ++r) {
                int gr = row0 + mi * 16 + rb + r;
                if (gr >= n) continue;
                float v = acc[mi][ni][r] + bias[ni];
                if (kind == 0) {
                    Qb[(size_t)gr * 512 + gc] = f2bf(v);
                } else if (kind == 1) {
                    unsigned enc = (unsigned)__builtin_amdgcn_cvt_pk_fp8_f32(v, v, 0, false);
                    KV[(size_t)gr * 1024 + (gc - 512)] = (unsigned char)enc;
                } else if (kind == 2) {
                    unsigned enc = (unsigned)__builtin_amdgcn_cvt_pk_fp8_f32(v, v, 0, false);
                    KV[(size_t)gr * 1024 + 512 + (gc - 1024)] = (unsigned char)enc;
                } else {
                    Sb[(size_t)gr * 128 + (gc - 1536)] = f2bf(v);
                }
            }
        }
    }
}

// ---------------- fused attention + head-mean + skip + relu ----------------
// One wave per dst node, all 4 heads. Lane i owns channels [8i,8i+8) of the
// 512-wide rows (head = lane>>4). K/V are fp8 e4m3, interleaved per node:
// KV[node][0..511] = K, KV[node][512..1023] = V.

__device__ __forceinline__ void unpack8(uint4 r, float* f) {
    f[0] = __uint_as_float(r.x << 16);
    f[1] = __uint_as_float(r.x & 0xffff0000u);
    f[2] = __uint_as_float(r.y << 16);
    f[3] = __uint_as_float(r.y & 0xffff0000u);
    f[4] = __uint_as_float(r.z << 16);
    f[5] = __uint_as_float(r.z & 0xffff0000u);
    f[6] = __uint_as_float(r.w << 16);
    f[7] = __uint_as_float(r.w & 0xffff0000u);
}

__device__ __forceinline__ void decf8(uint2 r, float* f) {
    fx2 a = __builtin_amdgcn_cvt_pk_f32_fp8(r.x, false);
    fx2 b = __builtin_amdgcn_cvt_pk_f32_fp8(r.x, true);
    fx2 c = __builtin_amdgcn_cvt_pk_f32_fp8(r.y, false);
    fx2 d = __builtin_amdgcn_cvt_pk_f32_fp8(r.y, true);
    f[0] = a[0]; f[1] = a[1]; f[2] = b[0]; f[3] = b[1];
    f[4] = c[0]; f[5] = c[1]; f[6] = d[0]; f[7] = d[1];
}

__device__ __forceinline__ float dotf8(const float* q, uint2 r) {
    float f[8];
    decf8(r, f);
    float p = 0.f;
#pragma unroll
    for (int j = 0; j < 8; ++j) p = fmaf(q[j], f[j], p);
    return p;
}

__device__ __forceinline__ void updf8(float& m, float& d, float* acc,
                                      float alpha, uint2 vr) {
    float vf[8];
    decf8(vr, vf);
    float nm = fmaxf(m, alpha);
    float sc = __expf(m - nm);    // first iter: exp(-inf)=0
    float w  = __expf(alpha - nm);
    d = d * sc + w;
#pragma unroll
    for (int j = 0; j < 8; ++j) acc[j] = acc[j] * sc + w * vf[j];
    m = nm;
}

__global__ __launch_bounds__(256) void attn_kernel(
    const short* __restrict__ Qb, const unsigned char* __restrict__ KV,
    const int* __restrict__ offs, const int* __restrict__ csr,
    const short* __restrict__ Sb, short* __restrict__ Xo, int n)
{
    int node = (blockIdx.x * blockDim.x + threadIdx.x) >> 6;
    if (node >= n) return;
    int lane = threadIdx.x & 63;

    float qf[8];
    {
        uint4 qr = *(const uint4*)&Qb[(size_t)node * 512 + lane * 8];
        unpack8(qr, qf);
    }

    int beg = offs[node], end = offs[node + 1];
    float m = -INFINITY, d = 0.f;
    float acc[8] = {};

    int e = beg;
    for (; e + 3 < end; e += 4) {
        int s0 = csr[e], s1 = csr[e + 1], s2 = csr[e + 2], s3 = csr[e + 3];
        const unsigned char* b0 = KV + (size_t)s0 * 1024 + lane * 8;
        const unsigned char* b1 = KV + (size_t)s1 * 1024 + lane * 8;
        const unsigned char* b2 = KV + (size_t)s2 * 1024 + lane * 8;
        const unsigned char* b3 = KV + (size_t)s3 * 1024 + lane * 8;
        uint2 k0 = *(const uint2*)b0;
        uint2 k1 = *(const uint2*)b1;
        uint2 k2 = *(const uint2*)b2;
        uint2 k3 = *(const uint2*)b3;
        uint2 v0 = *(const uint2*)(b0 + 512);
        uint2 v1 = *(const uint2*)(b1 + 512);
        uint2 v2 = *(const uint2*)(b2 + 512);
        uint2 v3 = *(const uint2*)(b3 + 512);
        float p0 = dotf8(qf, k0);
        float p1 = dotf8(qf, k1);
        float p2 = dotf8(qf, k2);
        float p3 = dotf8(qf, k3);
#pragma unroll
        for (int o = 1; o < 16; o <<= 1) {
            p0 += __shfl_xor(p0, o);
            p1 += __shfl_xor(p1, o);
            p2 += __shfl_xor(p2, o);
            p3 += __shfl_xor(p3, o);
        }
        updf8(m, d, acc, p0 * SCALE, v0);
        updf8(m, d, acc, p1 * SCALE, v1);
        updf8(m, d, acc, p2 * SCALE, v2);
        updf8(m, d, acc, p3 * SCALE, v3);
    }
    for (; e < end; ++e) {
        int s0 = csr[e];
        const unsigned char* b0 = KV + (size_t)s0 * 1024 + lane * 8;
        uint2 k0 = *(const uint2*)b0;
        uint2 v0 = *(const uint2*)(b0 + 512);
        float p0 = dotf8(qf, k0);
#pragma unroll
        for (int o = 1; o < 16; o <<= 1) p0 += __shfl_xor(p0, o);
        updf8(m, d, acc, p0 * SCALE, v0);
    }

    float inv = (d > 0.f) ? 1.f / d : 0.f;
#pragma unroll
    for (int j = 0; j < 8; ++j) acc[j] *= inv;

    // head mean across the 4 heads (lanes l, l^16, l^32, l^48 share channel)
#pragma unroll
    for (int j = 0; j < 8; ++j) {
        acc[j] += __shfl_xor(acc[j], 16);
        acc[j] += __shfl_xor(acc[j], 32);
    }

    if (lane < 16) {
        int c0 = lane * 8;
        float sf[8];
        uint4 sr = *(const uint4*)&Sb[(size_t)node * 128 + c0];
        unpack8(sr, sf);
        short8 o;
#pragma unroll
        for (int j = 0; j < 8; ++j)
            o[j] = f2bf(fmaxf(acc[j] * 0.25f + sf[j], 0.f));
        *(short8*)&Xo[(size_t)node * 128 + c0] = o;
    }
}

// ---------------- column sum + final sigmoid ----------------
__global__ void colsum_kernel(const short* __restrict__ X, float* __restrict__ g, int n) {
    int c = threadIdx.x;  // 128 threads
    int rpb = (n + gridDim.x - 1) / gridDim.x;
    int r0 = blockIdx.x * rpb;
    int r1 = min(r0 + rpb, n);
    float acc = 0.f;
    for (int r = r0; r < r1; ++r) acc += bf2f(X[r * DHID + c]);
    atomicAdd(&g[c], acc);
}

__global__ void final_kernel(const float* __restrict__ g, const float* __restrict__ Wfc,
                             const float* __restrict__ bfc, float* __restrict__ out, float invn) {
    __shared__ float red[128];
    int t = threadIdx.x;
    red[t] = g[t] * invn * Wfc[t];
    __syncthreads();
    for (int o = 64; o > 0; o >>= 1) {
        if (t < o) red[t] += red[t + o];
        __syncthreads();
    }
    if (t == 0) {
        float z = red[0] + bfc[0];
        out[0] = 1.f / (1.f + expf(-z));
    }
}

// ---------------- host ----------------

extern "C" void kernel_launch(void* const* d_in, const int* in_sizes, int n_in,
                              void* d_out, int out_size, void* d_ws, size_t ws_size,
                              hipStream_t stream) {
    const int N = NNODES, E = NEDGES;
    const float* x = (const float*)d_in[0];
    const int* ei = (const int*)d_in[1];
    const int* src = ei;
    const int* dst = ei + E;
    const float* Wfc = (const float*)d_in[26];
    const float* bfc = (const float*)d_in[27];

    size_t off = 0;
    auto alloc = [&](size_t bytes) -> char* {
        char* p = (char*)d_ws + off;
        off += (bytes + 255) & ~(size_t)255;
        return p;
    };
    int* deg   = (int*)alloc((size_t)N * 4);
    int* cnt   = (int*)alloc((size_t)N * 4);
    int* offs  = (int*)alloc((size_t)(N + 1) * 4);
    int* csr   = (int*)alloc((size_t)E * 4);
    short* Qb  = (short*)alloc((size_t)N * HC * 2);
    unsigned char* KV = (unsigned char*)alloc((size_t)N * 1024);
    short* Sb  = (short*)alloc((size_t)N * DHID * 2);
    short* xb0 = (short*)alloc((size_t)N * FIN0 * 2);
    short* xb1 = (short*)alloc((size_t)N * DHID * 2);
    short* xb2 = (short*)alloc((size_t)N * DHID * 2);
    short* WT  = (short*)alloc((size_t)NOUT * DHID * 2);
    float* bc  = (float*)alloc((size_t)NOUT * 4);
    float* g   = (float*)alloc(128 * 4);

    // CSR build (same graph for all layers)
    zero_ws_kernel<<<(N + 255) / 256, 256, 0, stream>>>(deg, g, N);
    count_kernel<<<(E + 255) / 256, 256, 0, stream>>>(dst, deg, E);
    scan_kernel<<<1, 256, 0, stream>>>(deg, offs, cnt, N, E);
    scatter_kernel<<<(E + 255) / 256, 256, 0, stream>>>(src, dst, offs, cnt, csr, E);

    // input -> bf16
    cvt_x_kernel<<<(N * FIN0 + 255) / 256, 256, 0, stream>>>(x, xb0, N * FIN0);

    int attn_blocks = (N + 3) / 4;   // 1 wave per node, 4 waves/block

    const short* xin = xb0;
    short* xouts[3] = { xb1, xb2, xb1 };
    for (int l = 0; l < 3; ++l) {
        int finShift = (l == 0) ? 6 : 7;
        int fin = 1 << finShift;
        const float* Wq = (const float*)d_in[2 + l * 8 + 0];
        const float* bq = (const float*)d_in[2 + l * 8 + 1];
        const float* Wk = (const float*)d_in[2 + l * 8 + 2];
        const float* bk = (const float*)d_in[2 + l * 8 + 3];
        const float* Wv = (const float*)d_in[2 + l * 8 + 4];
        const float* bv = (const float*)d_in[2 + l * 8 + 5];
        const float* Wss= (const float*)d_in[2 + l * 8 + 6];
        const float* bs = (const float*)d_in[2 + l * 8 + 7];

        cvt_w_kernel<<<(NOUT * fin + 255) / 256, 256, 0, stream>>>(
            Wq, Wk, Wv, Wss, bq, bk, bv, bs, WT, bc, finShift);

        dim3 ggrid((N + 63) / 64, 7);
        if (l == 0)
            gemm_qkvs_mfma<64><<<ggrid, 256, 0, stream>>>(xin, N, WT, bc, Qb, KV, Sb);
        else
            gemm_qkvs_mfma<128><<<ggrid, 256, 0, stream>>>(xin, N, WT, bc, Qb, KV, Sb);
        attn_kernel<<<attn_blocks, 256, 0, stream>>>(Qb, KV, offs, csr, Sb, xouts[l], N);
        xin = xouts[l];
    }

    colsum_kernel<<<256, 128, 0, stream>>>(xb1, g, N);
    final_kernel<<<1, 128, 0, stream>>>(g, Wfc, bfc, (float*)d_out, 1.0f / N);
}